// Round 4
// baseline (1703.762 us; speedup 1.0000x reference)
//
#include <hip/hip_runtime.h>
#include <hip/hip_bf16.h>
#include <math.h>

// SpKBGAT: N=50000, D=200, R=500, NHID=100, H=2, OD=200, E=150000, ENH=30000.
// I/O dtype is FLOAT32 (reference is all jnp.float32). Internal projections
// stored bf16 to keep workspace at ~41.4 MB.
#define DD   200
#define NHID 100
#define OD   200

static inline int cdiv(int a, int b) { return (a + b - 1) / b; }

__device__ inline float toF(float x) { return x; }
__device__ inline float toF(__hip_bfloat16 x) { return __bfloat162float(x); }
__device__ inline void storeC(float v, float* p) { *p = v; }
__device__ inline void storeC(float v, __hip_bfloat16* p) { *p = __float2bfloat16(v); }

// -------- per-row inverse L2 norm (f32 input), wave per row --------
__global__ __launch_bounds__(256)
void rownorm_inv_k(const float* __restrict__ in, float* __restrict__ sc, int M, int Dd)
{
    int wave = (blockIdx.x * blockDim.x + threadIdx.x) >> 6;
    int lane = threadIdx.x & 63;
    if (wave >= M) return;
    float ss = 0.f;
    for (int k = lane; k < Dd; k += 64) {
        float x = in[(size_t)wave * Dd + k];
        ss += x * x;
    }
    for (int o = 32; o > 0; o >>= 1) ss += __shfl_down(ss, o);
    if (lane == 0) sc[wave] = 1.f / fmaxf(sqrtf(ss), 1e-12f);
}

// -------- final in-place l2norm of f32 rows --------
__global__ __launch_bounds__(256)
void l2norm_rows_k(float* __restrict__ buf, int M, int Dd)
{
    int wave = (blockIdx.x * blockDim.x + threadIdx.x) >> 6;
    int lane = threadIdx.x & 63;
    if (wave >= M) return;
    float v[4];
    float ss = 0.f;
    int cnt = 0;
    for (int k = lane; k < Dd; k += 64) {
        float x = buf[(size_t)wave * Dd + k];
        v[cnt++] = x;
        ss += x * x;
    }
    for (int o = 32; o > 0; o >>= 1) ss += __shfl_down(ss, o);
    ss = __shfl(ss, 0);
    float sc = 1.f / fmaxf(sqrtf(ss), 1e-12f);
    cnt = 0;
    for (int k = lane; k < Dd; k += 64)
        buf[(size_t)wave * Dd + k] = v[cnt++] * sc;
}

// -------- tiled GEMM: C[M,Nc] = (A[M,K] * ascale[m]?) * B --------
// BTr=true : B row-major [Nc, ldb], element B[n*ldb + colOff + k]  (C = A * B_subT)
// BTr=false: B row-major [K,  ldb], element B[k*ldb + n]           (C = A * B)
// ACC=true : C += result.
template<bool BTr, bool ACC, typename AT, typename BT2, typename CT>
__global__ __launch_bounds__(256)
void gemm_k(const AT* __restrict__ A, int lda, const float* __restrict__ ascale,
            const BT2* __restrict__ B, int ldb, int colOff,
            CT* __restrict__ C, int ldc, int M, int Nc, int K)
{
    __shared__ float As[16][65];
    __shared__ float Bs[16][65];
    int tid = threadIdx.x;
    int m0 = blockIdx.x * 64;
    int n0 = blockIdx.y * 64;
    int ty = tid >> 4, tx = tid & 15;
    float acc[4][4] = {};

    for (int k0 = 0; k0 < K; k0 += 16) {
        {   // A tile 64x16
            int k = tid & 15, mb = tid >> 4;
#pragma unroll
            for (int i = 0; i < 4; i++) {
                int m = mb + i * 16;
                int gm = m0 + m, gk = k0 + k;
                float v = 0.f;
                if (gm < M && gk < K) {
                    v = toF(A[(size_t)gm * lda + gk]);
                    if (ascale) v *= ascale[gm];
                }
                As[k][m] = v;
            }
        }
        if (BTr) {
            int k = tid & 15, nb = tid >> 4;
#pragma unroll
            for (int i = 0; i < 4; i++) {
                int n = nb + i * 16;
                int gn = n0 + n, gk = k0 + k;
                float v = 0.f;
                if (gn < Nc && gk < K) v = toF(B[(size_t)gn * ldb + colOff + gk]);
                Bs[k][n] = v;
            }
        } else {
            int n = tid & 63, kb = tid >> 6;
#pragma unroll
            for (int i = 0; i < 4; i++) {
                int k = kb + i * 4;
                int gn = n0 + n, gk = k0 + k;
                float v = 0.f;
                if (gn < Nc && gk < K) v = toF(B[(size_t)gk * ldb + gn]);
                Bs[k][n] = v;
            }
        }
        __syncthreads();
#pragma unroll
        for (int kk = 0; kk < 16; kk++) {
            float a[4], b[4];
#pragma unroll
            for (int i = 0; i < 4; i++) a[i] = As[kk][ty * 4 + i];
#pragma unroll
            for (int j = 0; j < 4; j++) b[j] = Bs[kk][tx * 4 + j];
#pragma unroll
            for (int i = 0; i < 4; i++)
#pragma unroll
                for (int j = 0; j < 4; j++)
                    acc[i][j] += a[i] * b[j];
        }
        __syncthreads();
    }
#pragma unroll
    for (int i = 0; i < 4; i++) {
        int gm = m0 + ty * 4 + i;
        if (gm >= M) continue;
#pragma unroll
        for (int j = 0; j < 4; j++) {
            int gn = n0 + tx * 4 + j;
            if (gn < Nc) {
                CT* p = &C[(size_t)gm * ldc + gn];
                float v = acc[i][j];
                if (ACC) v += toF(*p);
                storeC(v, p);
            }
        }
    }
}

// -------- row-dot: out[m] = dot(mat[m, coff:coff+Dd], vec) --------
template<typename T>
__global__ __launch_bounds__(256)
void rowdot_k(const T* __restrict__ mat, int ld, int coff,
              const float* __restrict__ vec,
              float* __restrict__ outp, int M, int Dd)
{
    int wave = (blockIdx.x * blockDim.x + threadIdx.x) >> 6;
    int lane = threadIdx.x & 63;
    if (wave >= M) return;
    float s = 0.f;
    for (int k = lane; k < Dd; k += 64)
        s += toF(mat[(size_t)wave * ld + coff + k]) * vec[k];
    for (int o = 32; o > 0; o >>= 1) s += __shfl_down(s, o);
    if (lane == 0) outp[wave] = s;
}

// -------- edge scatter pass over 50 feature columns, wave per edge --------
__global__ __launch_bounds__(256)
void edge_pass_k(const int* __restrict__ el, int E, const int* __restrict__ etype,
                 const int* __restrict__ tin, int Etot,
                 const float* __restrict__ s1, const float* __restrict__ s2,
                 const float* __restrict__ srel,
                 const __hip_bfloat16* __restrict__ xsrc, int xld, int xoff,
                 const float* __restrict__ rp, int rld, int roff,
                 float* __restrict__ rowsum, int doRowsum,
                 float* __restrict__ acc)   // [N, 50]
{
    int wave = (blockIdx.x * blockDim.x + threadIdx.x) >> 6;
    int lane = threadIdx.x & 63;
    if (wave >= Etot) return;
    int dst, src, r1, r2;
    if (wave < E) {
        dst = el[wave]; src = el[E + wave];
        r1 = etype[wave]; r2 = -1;
    } else {
        int j = wave - E;
        dst = tin[j * 4 + 3]; src = tin[j * 4 + 0];
        r1 = tin[j * 4 + 1];  r2 = tin[j * 4 + 2];
    }
    float z = s1[dst] + s2[src] + srel[r1] + (r2 >= 0 ? srel[r2] : 0.f);
    float lz = z > 0.f ? z : 0.2f * z;
    float w = expf(-lz);
    if (doRowsum && lane == 0) atomicAdd(&rowsum[dst], w);
    const __hip_bfloat16* xs = xsrc + (size_t)src * xld + xoff;
    const float* rp1 = rp + (size_t)r1 * rld + roff;
    const float* rp2 = (r2 >= 0) ? (rp + (size_t)r2 * rld + roff) : rp1;
    if (lane < 50) {
        float v = __bfloat162float(xs[lane]) + rp1[lane] + (r2 >= 0 ? rp2[lane] : 0.f);
        atomicAdd(&acc[(size_t)dst * 50 + lane], w * v);
    }
}

// -------- layer-1 finalize (in place on bf16 x1 slice): x1 = elu(x1 + acc/rs)
__global__ void finalize50_k(__hip_bfloat16* __restrict__ x1, int coff,
                             const float* __restrict__ acc,
                             const float* __restrict__ rowsum, int N)
{
    int i = blockIdx.x * blockDim.x + threadIdx.x;
    if (i >= N * 50) return;
    int n = i / 50, k = i - n * 50;
    size_t idx = (size_t)n * OD + coff + k;
    float rs = rowsum[n];
    float hp = rs > 0.f ? __bfloat162float(x1[idx]) + acc[i] / rs : 0.f;
    float e = hp > 0.f ? hp : expf(hp) - 1.f;
    x1[idx] = __float2bfloat16(e);
}

// -------- layer-2 combine (in place on f32 out_ent holding x1A1): ---------
// out_ent = mask * elu(x1A1 + acc/rs)
__global__ void combine50_k(float* __restrict__ outent, int coff,
                            const float* __restrict__ acc,
                            const float* __restrict__ rowsum,
                            const float* __restrict__ maskf, int N)
{
    int i = blockIdx.x * blockDim.x + threadIdx.x;
    if (i >= N * 50) return;
    int n = i / 50, k = i - n * 50;
    size_t idx = (size_t)n * OD + coff + k;
    float rs = rowsum[n];
    float hp = rs > 0.f ? outent[idx] + acc[i] / rs : 0.f;
    float e = hp > 0.f ? hp : expf(hp) - 1.f;
    outent[idx] = maskf[n] * e;
}

// -------- mask scatter (f32 output doubles as mask operand) --------
__global__ void scatter_mask_k(const int* __restrict__ batch, int NB,
                               float* __restrict__ masko)
{
    int i = blockIdx.x * blockDim.x + threadIdx.x;
    if (i >= NB) return;
    masko[batch[i]] = 1.0f;
}

extern "C" void kernel_launch(void* const* d_in, const int* in_sizes, int n_in,
                              void* d_out, int out_size, void* d_ws, size_t ws_size,
                              hipStream_t stream)
{
    const float* ent      = (const float*)d_in[0];   // [N, 200]
    const float* rel      = (const float*)d_in[1];   // [500, 200]
    const float* W_ent    = (const float*)d_in[2];   // [200, 200]
    const float* W_gat    = (const float*)d_in[3];   // [200, 200]
    const float* a_heads  = (const float*)d_in[4];   // [2, 100, 600]
    const float* a2_heads = (const float*)d_in[5];   // [2, 1, 100]
    const float* a_out    = (const float*)d_in[6];   // [200, 600]
    const float* a2_out   = (const float*)d_in[7];   // [1, 200]
    const int* batch = (const int*)d_in[8];
    const int* el    = (const int*)d_in[9];
    const int* etype = (const int*)d_in[10];
    const int* tin   = (const int*)d_in[11];

    const int N   = in_sizes[0] / DD;   // 50000
    const int R   = in_sizes[1] / DD;   // 500
    const int NB  = in_sizes[8];        // 20000
    const int E   = in_sizes[9] / 2;    // 150000
    const int ENH = in_sizes[11] / 4;   // 30000
    const int Etot = E + ENH;

    // ---- workspace layout (~41.4 MB) ----
    char* ws = (char*)d_ws;
    size_t off = 0;
    auto take = [&](size_t bytes) { size_t o = off; off += (bytes + 255) & ~(size_t)255; return o; };
    size_t o_R1   = take((size_t)N * OD * 2);  // x1 bf16 [N,200]; later accX2 f32 [N,50]
    size_t o_R2   = take((size_t)N * OD * 2);  // pBh bf16 [N,100] + accX1 f32 [N,50]; later x1A2 bf16 [N,200]
    size_t o_rpf  = take((size_t)R * OD * 4);  // f32 relation projections
    size_t o_nsc  = take((size_t)N * 4);
    size_t o_s1   = take((size_t)N * 4);
    size_t o_s2   = take((size_t)N * 4);
    size_t o_rows = take((size_t)N * 4);
    size_t o_srel = take((size_t)R * 4);

    __hip_bfloat16* x1    = (__hip_bfloat16*)(ws + o_R1);
    float*          accX2 = (float*)(ws + o_R1);                        // after x1 dead
    __hip_bfloat16* pBh   = (__hip_bfloat16*)(ws + o_R2);               // [N,100] bf16
    float*          accX1 = (float*)(ws + o_R2 + (size_t)N * NHID * 2); // [N,50] f32
    __hip_bfloat16* x1A2  = (__hip_bfloat16*)(ws + o_R2);               // after pBh/accX1 dead
    float* rpf    = (float*)(ws + o_rpf);
    float* nscale = (float*)(ws + o_nsc);
    float* s1     = (float*)(ws + o_s1);
    float* s2     = (float*)(ws + o_s2);
    float* rowsum = (float*)(ws + o_rows);
    float* srel   = (float*)(ws + o_srel);

    float* out       = (float*)d_out;
    float* out_ent   = out;                                     // [N,200]
    float* out_rel_o = out + (size_t)N * OD;                    // [500,200]
    float* out_mask  = out + (size_t)N * OD + (size_t)R * OD;   // [N]

    // A. per-row inverse norms; out_rel = rel @ W_gat (f32 -> d_out)
    rownorm_inv_k<<<cdiv(N, 4), 256, 0, stream>>>(ent, nscale, N, DD);
    gemm_k<false, false, float, float, float><<<dim3(cdiv(R, 64), cdiv(OD, 64)), 256, 0, stream>>>(
        rel, DD, nullptr, W_gat, OD, 0, out_rel_o, OD, R, OD, DD);

    // B. layer-1 per head: projections + attention + aggregation
    for (int h = 0; h < 2; h++) {
        const float* ah  = a_heads + (size_t)h * NHID * 600;
        const float* a2h = a2_heads + (size_t)h * NHID;
        gemm_k<true, false, float, float, __hip_bfloat16><<<dim3(cdiv(N, 64), cdiv(NHID, 64)), 256, 0, stream>>>(
            ent, DD, nscale, ah, 600, 0,   x1 + h * NHID, OD, N, NHID, DD);   // xa1 -> x1 slice
        gemm_k<true, false, float, float, __hip_bfloat16><<<dim3(cdiv(N, 64), cdiv(NHID, 64)), 256, 0, stream>>>(
            ent, DD, nscale, ah, 600, 200, pBh, NHID, N, NHID, DD);           // xa2 -> pBh
        gemm_k<true, false, float, float, float><<<dim3(cdiv(R, 64), cdiv(NHID, 64)), 256, 0, stream>>>(
            rel, DD, nullptr, ah, 600, 400, rpf, NHID, R, NHID, DD);          // relproj -> rpf
        rowdot_k<__hip_bfloat16><<<cdiv(N, 4), 256, 0, stream>>>(x1, OD, h * NHID, a2h, s1, N, NHID);
        rowdot_k<__hip_bfloat16><<<cdiv(N, 4), 256, 0, stream>>>(pBh, NHID, 0, a2h, s2, N, NHID);
        rowdot_k<float><<<cdiv(R, 4), 256, 0, stream>>>(rpf, NHID, 0, a2h, srel, R, NHID);
        hipMemsetAsync(rowsum, 0, (size_t)N * 4, stream);
        for (int q = 0; q < 2; q++) {
            hipMemsetAsync(accX1, 0, (size_t)N * 50 * 4, stream);
            edge_pass_k<<<cdiv(Etot, 4), 256, 0, stream>>>(
                el, E, etype, tin, Etot, s1, s2, srel,
                pBh, NHID, q * 50, rpf, NHID, q * 50, rowsum, q == 0 ? 1 : 0, accX1);
            finalize50_k<<<cdiv(N * 50, 256), 256, 0, stream>>>(
                x1, h * NHID + q * 50, accX1, rowsum, N);
        }
    }
    // pBh/accX1 dead; R2 becomes x1A2.

    // C. layer-2 projections + logit components (x1A1 in f32 out_ent region)
    gemm_k<true, false, __hip_bfloat16, float, float><<<dim3(cdiv(N, 64), cdiv(OD, 64)), 256, 0, stream>>>(
        x1, OD, nullptr, a_out, 600, 0,   out_ent, OD, N, OD, OD);
    gemm_k<true, false, __hip_bfloat16, float, __hip_bfloat16><<<dim3(cdiv(N, 64), cdiv(OD, 64)), 256, 0, stream>>>(
        x1, OD, nullptr, a_out, 600, 200, x1A2, OD, N, OD, OD);
    gemm_k<true, false, float, float, float><<<dim3(cdiv(R, 64), cdiv(OD, 64)), 256, 0, stream>>>(
        out_rel_o, OD, nullptr, a_out, 600, 400, rpf, OD, R, OD, OD);
    rowdot_k<float><<<cdiv(N, 4), 256, 0, stream>>>(out_ent, OD, 0, a2_out, s1, N, OD);
    rowdot_k<__hip_bfloat16><<<cdiv(N, 4), 256, 0, stream>>>(x1A2, OD, 0, a2_out, s2, N, OD);
    rowdot_k<float><<<cdiv(R, 4), 256, 0, stream>>>(rpf, OD, 0, a2_out, srel, R, OD);
    // x1 dead; R1 becomes accX2.

    // D. mask; layer-2 aggregation in 4 quarter passes; combine in place
    hipMemsetAsync(out_mask, 0, (size_t)N * 4, stream);
    scatter_mask_k<<<cdiv(NB, 256), 256, 0, stream>>>(batch, NB, out_mask);
    hipMemsetAsync(rowsum, 0, (size_t)N * 4, stream);
    for (int q = 0; q < 4; q++) {
        hipMemsetAsync(accX2, 0, (size_t)N * 50 * 4, stream);
        edge_pass_k<<<cdiv(Etot, 4), 256, 0, stream>>>(
            el, E, etype, tin, Etot, s1, s2, srel,
            x1A2, OD, q * 50, rpf, OD, q * 50, rowsum, q == 0 ? 1 : 0, accX2);
        combine50_k<<<cdiv(N * 50, 256), 256, 0, stream>>>(
            out_ent, q * 50, accX2, rowsum, out_mask, N);
    }

    // E. out_ent += l2norm(ent) @ W_entities  (accumulate)
    gemm_k<false, true, float, float, float><<<dim3(cdiv(N, 64), cdiv(OD, 64)), 256, 0, stream>>>(
        ent, DD, nscale, W_ent, OD, 0, out_ent, OD, N, OD, DD);

    // F. in-place row l2norm of out_ent
    l2norm_rows_k<<<cdiv(N, 4), 256, 0, stream>>>(out_ent, N, OD);
}

// Round 5
// 1484.012 us; speedup vs baseline: 1.1481x; 1.1481x over previous
//
#include <hip/hip_runtime.h>
#include <hip/hip_bf16.h>
#include <math.h>

// SpKBGAT: N=50000, D=200, R=500, NHID=100, H=2, OD=200, E=150000, ENH=30000.
// All I/O fp32. Internal projections bf16 (ws ~41.4 MB, proven in R4).
// R5: big GEMMs moved to MFMA (16x16x32 bf16), fp32 accumulate.
#define DD   200
#define NHID 100
#define OD   200

#define BM 64
#define BN 64
#define BK 32
#define KPAD 48   // LDS row stride in elements (96 B, 16B-aligned for b128)

typedef __attribute__((ext_vector_type(8))) short short8;
typedef __attribute__((ext_vector_type(4))) float f32x4;

static inline int cdiv(int a, int b) { return (a + b - 1) / b; }

__device__ inline float toF(float x) { return x; }
__device__ inline float toF(__hip_bfloat16 x) { return __bfloat162float(x); }
__device__ inline void storeC(float v, float* p) { *p = v; }
__device__ inline void storeC(float v, __hip_bfloat16* p) { *p = __float2bfloat16(v); }

// -------- per-row inverse L2 norm (f32 input), wave per row --------
__global__ __launch_bounds__(256)
void rownorm_inv_k(const float* __restrict__ in, float* __restrict__ sc, int M, int Dd)
{
    int wave = (blockIdx.x * blockDim.x + threadIdx.x) >> 6;
    int lane = threadIdx.x & 63;
    if (wave >= M) return;
    float ss = 0.f;
    for (int k = lane; k < Dd; k += 64) {
        float x = in[(size_t)wave * Dd + k];
        ss += x * x;
    }
    for (int o = 32; o > 0; o >>= 1) ss += __shfl_down(ss, o);
    if (lane == 0) sc[wave] = 1.f / fmaxf(sqrtf(ss), 1e-12f);
}

// -------- final in-place l2norm of f32 rows --------
__global__ __launch_bounds__(256)
void l2norm_rows_k(float* __restrict__ buf, int M, int Dd)
{
    int wave = (blockIdx.x * blockDim.x + threadIdx.x) >> 6;
    int lane = threadIdx.x & 63;
    if (wave >= M) return;
    float v[4];
    float ss = 0.f;
    int cnt = 0;
    for (int k = lane; k < Dd; k += 64) {
        float x = buf[(size_t)wave * Dd + k];
        v[cnt++] = x;
        ss += x * x;
    }
    for (int o = 32; o > 0; o >>= 1) ss += __shfl_down(ss, o);
    ss = __shfl(ss, 0);
    float sc = 1.f / fmaxf(sqrtf(ss), 1e-12f);
    cnt = 0;
    for (int k = lane; k < Dd; k += 64)
        buf[(size_t)wave * Dd + k] = v[cnt++] * sc;
}

// -------- MFMA GEMM: C[M,Nc] = (A[M,K] * ascale[m]?) * B --------
// BTr=true : B row-major [Nc_tot, ldb], element B[n*ldb + colOff + k]  (C = A * B_subT)
// BTr=false: B row-major [K, ldb],      element B[k*ldb + n]           (C = A * B)
// ACC=true : C += result.
// Grid: (cdiv(Nc,BN), cdiv(M,BM)) — N on x so consecutive blocks share A rows.
template<bool BTr, bool ACC, typename AT, typename CT>
__global__ __launch_bounds__(256)
void gemm_mfma_k(const AT* __restrict__ A, int lda, const float* __restrict__ ascale,
                 const float* __restrict__ B, int ldb, int colOff,
                 CT* __restrict__ C, int ldc, int M, int Nc, int K)
{
    __shared__ __align__(16) __hip_bfloat16 As[BM][KPAD];
    __shared__ __align__(16) __hip_bfloat16 Bs[BN][KPAD];
    int tid  = threadIdx.x;
    int wave = tid >> 6, lane = tid & 63;
    int quad = lane >> 4, l16 = lane & 15;
    int n0 = blockIdx.x * BN, m0 = blockIdx.y * BM;

    f32x4 acc[4];
#pragma unroll
    for (int t = 0; t < 4; t++) acc[t] = (f32x4){0.f, 0.f, 0.f, 0.f};

    for (int k0 = 0; k0 < K; k0 += BK) {
        {   // stage A tile 64x32: thread t -> row t>>2, k-chunk (t&3)*8
            int m = tid >> 2, kc = (tid & 3) * 8;
            int gm = m0 + m;
            float scale = (ascale && gm < M) ? ascale[gm] : 1.f;
#pragma unroll
            for (int j = 0; j < 8; j++) {
                int gk = k0 + kc + j;
                float v = 0.f;
                if (gm < M && gk < K) v = toF(A[(size_t)gm * lda + gk]) * scale;
                As[m][kc + j] = __float2bfloat16(v);
            }
        }
        if (BTr) {  // B_subT[n][k] = B[n*ldb + colOff + k] : same pattern as A
            int n = tid >> 2, kc = (tid & 3) * 8;
            int gn = n0 + n;
#pragma unroll
            for (int j = 0; j < 8; j++) {
                int gk = k0 + kc + j;
                float v = 0.f;
                if (gn < Nc && gk < K) v = B[(size_t)gn * ldb + colOff + gk];
                Bs[n][kc + j] = __float2bfloat16(v);
            }
        } else {    // Bt[n][k] = B[k*ldb + n]; lane-consecutive n => coalesced
            int n = tid & 63, kq = tid >> 6;
            int gn = n0 + n;
#pragma unroll
            for (int j = 0; j < 8; j++) {
                int gk = k0 + kq * 8 + j;
                float v = 0.f;
                if (gn < Nc && gk < K) v = B[(size_t)gk * ldb + gn];
                Bs[n][kq * 8 + j] = __float2bfloat16(v);
            }
        }
        __syncthreads();
        // wave computes rows [wave*16, wave*16+16) x cols [0,64)
        short8 a = *(const short8*)&As[wave * 16 + l16][quad * 8];
#pragma unroll
        for (int t = 0; t < 4; t++) {
            short8 b = *(const short8*)&Bs[t * 16 + l16][quad * 8];
            acc[t] = __builtin_amdgcn_mfma_f32_16x16x32_bf16(a, b, acc[t], 0, 0, 0);
        }
        __syncthreads();
    }
    // epilogue: C/D layout col=lane&15, row=quad*4+reg
#pragma unroll
    for (int t = 0; t < 4; t++) {
        int gn = n0 + t * 16 + l16;
        if (gn >= Nc) continue;
#pragma unroll
        for (int i = 0; i < 4; i++) {
            int gm = m0 + wave * 16 + quad * 4 + i;
            if (gm < M) {
                CT* p = &C[(size_t)gm * ldc + gn];
                float v = acc[t][i];
                if (ACC) v += toF(*p);
                storeC(v, p);
            }
        }
    }
}

// -------- row-dot: out[m] = dot(mat[m, coff:coff+Dd], vec) --------
template<typename T>
__global__ __launch_bounds__(256)
void rowdot_k(const T* __restrict__ mat, int ld, int coff,
              const float* __restrict__ vec,
              float* __restrict__ outp, int M, int Dd)
{
    int wave = (blockIdx.x * blockDim.x + threadIdx.x) >> 6;
    int lane = threadIdx.x & 63;
    if (wave >= M) return;
    float s = 0.f;
    for (int k = lane; k < Dd; k += 64)
        s += toF(mat[(size_t)wave * ld + coff + k]) * vec[k];
    for (int o = 32; o > 0; o >>= 1) s += __shfl_down(s, o);
    if (lane == 0) outp[wave] = s;
}

// -------- edge scatter pass over 50 feature columns, wave per edge --------
__global__ __launch_bounds__(256)
void edge_pass_k(const int* __restrict__ el, int E, const int* __restrict__ etype,
                 const int* __restrict__ tin, int Etot,
                 const float* __restrict__ s1, const float* __restrict__ s2,
                 const float* __restrict__ srel,
                 const __hip_bfloat16* __restrict__ xsrc, int xld, int xoff,
                 const float* __restrict__ rp, int rld, int roff,
                 float* __restrict__ rowsum, int doRowsum,
                 float* __restrict__ acc)   // [N, 50]
{
    int wave = (blockIdx.x * blockDim.x + threadIdx.x) >> 6;
    int lane = threadIdx.x & 63;
    if (wave >= Etot) return;
    int dst, src, r1, r2;
    if (wave < E) {
        dst = el[wave]; src = el[E + wave];
        r1 = etype[wave]; r2 = -1;
    } else {
        int j = wave - E;
        dst = tin[j * 4 + 3]; src = tin[j * 4 + 0];
        r1 = tin[j * 4 + 1];  r2 = tin[j * 4 + 2];
    }
    float z = s1[dst] + s2[src] + srel[r1] + (r2 >= 0 ? srel[r2] : 0.f);
    float lz = z > 0.f ? z : 0.2f * z;
    float w = expf(-lz);
    if (doRowsum && lane == 0) atomicAdd(&rowsum[dst], w);
    const __hip_bfloat16* xs = xsrc + (size_t)src * xld + xoff;
    const float* rp1 = rp + (size_t)r1 * rld + roff;
    const float* rp2 = (r2 >= 0) ? (rp + (size_t)r2 * rld + roff) : rp1;
    if (lane < 50) {
        float v = __bfloat162float(xs[lane]) + rp1[lane] + (r2 >= 0 ? rp2[lane] : 0.f);
        atomicAdd(&acc[(size_t)dst * 50 + lane], w * v);
    }
}

// -------- layer-1 finalize (in place on bf16 x1 slice): x1 = elu(x1 + acc/rs)
__global__ void finalize50_k(__hip_bfloat16* __restrict__ x1, int coff,
                             const float* __restrict__ acc,
                             const float* __restrict__ rowsum, int N)
{
    int i = blockIdx.x * blockDim.x + threadIdx.x;
    if (i >= N * 50) return;
    int n = i / 50, k = i - n * 50;
    size_t idx = (size_t)n * OD + coff + k;
    float rs = rowsum[n];
    float hp = rs > 0.f ? __bfloat162float(x1[idx]) + acc[i] / rs : 0.f;
    float e = hp > 0.f ? hp : expf(hp) - 1.f;
    x1[idx] = __float2bfloat16(e);
}

// -------- layer-2 combine (in place on f32 out_ent holding x1A1): ---------
// out_ent = mask * elu(x1A1 + acc/rs)
__global__ void combine50_k(float* __restrict__ outent, int coff,
                            const float* __restrict__ acc,
                            const float* __restrict__ rowsum,
                            const float* __restrict__ maskf, int N)
{
    int i = blockIdx.x * blockDim.x + threadIdx.x;
    if (i >= N * 50) return;
    int n = i / 50, k = i - n * 50;
    size_t idx = (size_t)n * OD + coff + k;
    float rs = rowsum[n];
    float hp = rs > 0.f ? outent[idx] + acc[i] / rs : 0.f;
    float e = hp > 0.f ? hp : expf(hp) - 1.f;
    outent[idx] = maskf[n] * e;
}

// -------- mask scatter (f32 output doubles as mask operand) --------
__global__ void scatter_mask_k(const int* __restrict__ batch, int NB,
                               float* __restrict__ masko)
{
    int i = blockIdx.x * blockDim.x + threadIdx.x;
    if (i >= NB) return;
    masko[batch[i]] = 1.0f;
}

extern "C" void kernel_launch(void* const* d_in, const int* in_sizes, int n_in,
                              void* d_out, int out_size, void* d_ws, size_t ws_size,
                              hipStream_t stream)
{
    const float* ent      = (const float*)d_in[0];   // [N, 200]
    const float* rel      = (const float*)d_in[1];   // [500, 200]
    const float* W_ent    = (const float*)d_in[2];   // [200, 200]
    const float* W_gat    = (const float*)d_in[3];   // [200, 200]
    const float* a_heads  = (const float*)d_in[4];   // [2, 100, 600]
    const float* a2_heads = (const float*)d_in[5];   // [2, 1, 100]
    const float* a_out    = (const float*)d_in[6];   // [200, 600]
    const float* a2_out   = (const float*)d_in[7];   // [1, 200]
    const int* batch = (const int*)d_in[8];
    const int* el    = (const int*)d_in[9];
    const int* etype = (const int*)d_in[10];
    const int* tin   = (const int*)d_in[11];

    const int N   = in_sizes[0] / DD;   // 50000
    const int R   = in_sizes[1] / DD;   // 500
    const int NB  = in_sizes[8];        // 20000
    const int E   = in_sizes[9] / 2;    // 150000
    const int ENH = in_sizes[11] / 4;   // 30000
    const int Etot = E + ENH;

    // ---- workspace layout (~41.4 MB, same as R4) ----
    char* ws = (char*)d_ws;
    size_t off = 0;
    auto take = [&](size_t bytes) { size_t o = off; off += (bytes + 255) & ~(size_t)255; return o; };
    size_t o_R1   = take((size_t)N * OD * 2);  // x1 bf16 [N,200]; later accX2 f32 [N,50]
    size_t o_R2   = take((size_t)N * OD * 2);  // pBh bf16 [N,100] + accX1 f32 [N,50]; later x1A2 bf16 [N,200]
    size_t o_rpf  = take((size_t)R * OD * 4);  // f32 relation projections
    size_t o_nsc  = take((size_t)N * 4);
    size_t o_s1   = take((size_t)N * 4);
    size_t o_s2   = take((size_t)N * 4);
    size_t o_rows = take((size_t)N * 4);
    size_t o_srel = take((size_t)R * 4);

    __hip_bfloat16* x1    = (__hip_bfloat16*)(ws + o_R1);
    float*          accX2 = (float*)(ws + o_R1);                        // after x1 dead
    __hip_bfloat16* pBh   = (__hip_bfloat16*)(ws + o_R2);               // [N,100] bf16
    float*          accX1 = (float*)(ws + o_R2 + (size_t)N * NHID * 2); // [N,50] f32
    __hip_bfloat16* x1A2  = (__hip_bfloat16*)(ws + o_R2);               // after pBh/accX1 dead
    float* rpf    = (float*)(ws + o_rpf);
    float* nscale = (float*)(ws + o_nsc);
    float* s1     = (float*)(ws + o_s1);
    float* s2     = (float*)(ws + o_s2);
    float* rowsum = (float*)(ws + o_rows);
    float* srel   = (float*)(ws + o_srel);

    float* out       = (float*)d_out;
    float* out_ent   = out;                                     // [N,200]
    float* out_rel_o = out + (size_t)N * OD;                    // [500,200]
    float* out_mask  = out + (size_t)N * OD + (size_t)R * OD;   // [N]

    // A. per-row inverse norms; out_rel = rel @ W_gat (f32 -> d_out)
    rownorm_inv_k<<<cdiv(N, 4), 256, 0, stream>>>(ent, nscale, N, DD);
    gemm_mfma_k<false, false, float, float><<<dim3(cdiv(OD, BN), cdiv(R, BM)), 256, 0, stream>>>(
        rel, DD, nullptr, W_gat, OD, 0, out_rel_o, OD, R, OD, DD);

    // B. layer-1 per head: projections + attention + aggregation
    for (int h = 0; h < 2; h++) {
        const float* ah  = a_heads + (size_t)h * NHID * 600;
        const float* a2h = a2_heads + (size_t)h * NHID;
        gemm_mfma_k<true, false, float, __hip_bfloat16><<<dim3(cdiv(NHID, BN), cdiv(N, BM)), 256, 0, stream>>>(
            ent, DD, nscale, ah, 600, 0,   x1 + h * NHID, OD, N, NHID, DD);   // xa1 -> x1 slice
        gemm_mfma_k<true, false, float, __hip_bfloat16><<<dim3(cdiv(NHID, BN), cdiv(N, BM)), 256, 0, stream>>>(
            ent, DD, nscale, ah, 600, 200, pBh, NHID, N, NHID, DD);           // xa2 -> pBh
        gemm_mfma_k<true, false, float, float><<<dim3(cdiv(NHID, BN), cdiv(R, BM)), 256, 0, stream>>>(
            rel, DD, nullptr, ah, 600, 400, rpf, NHID, R, NHID, DD);          // relproj -> rpf
        rowdot_k<__hip_bfloat16><<<cdiv(N, 4), 256, 0, stream>>>(x1, OD, h * NHID, a2h, s1, N, NHID);
        rowdot_k<__hip_bfloat16><<<cdiv(N, 4), 256, 0, stream>>>(pBh, NHID, 0, a2h, s2, N, NHID);
        rowdot_k<float><<<cdiv(R, 4), 256, 0, stream>>>(rpf, NHID, 0, a2h, srel, R, NHID);
        hipMemsetAsync(rowsum, 0, (size_t)N * 4, stream);
        for (int q = 0; q < 2; q++) {
            hipMemsetAsync(accX1, 0, (size_t)N * 50 * 4, stream);
            edge_pass_k<<<cdiv(Etot, 4), 256, 0, stream>>>(
                el, E, etype, tin, Etot, s1, s2, srel,
                pBh, NHID, q * 50, rpf, NHID, q * 50, rowsum, q == 0 ? 1 : 0, accX1);
            finalize50_k<<<cdiv(N * 50, 256), 256, 0, stream>>>(
                x1, h * NHID + q * 50, accX1, rowsum, N);
        }
    }
    // pBh/accX1 dead; R2 becomes x1A2.

    // C. layer-2 projections + logit components (x1A1 in f32 out_ent region)
    gemm_mfma_k<true, false, __hip_bfloat16, float><<<dim3(cdiv(OD, BN), cdiv(N, BM)), 256, 0, stream>>>(
        x1, OD, nullptr, a_out, 600, 0,   out_ent, OD, N, OD, OD);
    gemm_mfma_k<true, false, __hip_bfloat16, __hip_bfloat16><<<dim3(cdiv(OD, BN), cdiv(N, BM)), 256, 0, stream>>>(
        x1, OD, nullptr, a_out, 600, 200, x1A2, OD, N, OD, OD);
    gemm_mfma_k<true, false, float, float><<<dim3(cdiv(OD, BN), cdiv(R, BM)), 256, 0, stream>>>(
        out_rel_o, OD, nullptr, a_out, 600, 400, rpf, OD, R, OD, OD);
    rowdot_k<float><<<cdiv(N, 4), 256, 0, stream>>>(out_ent, OD, 0, a2_out, s1, N, OD);
    rowdot_k<__hip_bfloat16><<<cdiv(N, 4), 256, 0, stream>>>(x1A2, OD, 0, a2_out, s2, N, OD);
    rowdot_k<float><<<cdiv(R, 4), 256, 0, stream>>>(rpf, OD, 0, a2_out, srel, R, OD);
    // x1 dead; R1 becomes accX2.

    // D. mask; layer-2 aggregation in 4 quarter passes; combine in place
    hipMemsetAsync(out_mask, 0, (size_t)N * 4, stream);
    scatter_mask_k<<<cdiv(NB, 256), 256, 0, stream>>>(batch, NB, out_mask);
    hipMemsetAsync(rowsum, 0, (size_t)N * 4, stream);
    for (int q = 0; q < 4; q++) {
        hipMemsetAsync(accX2, 0, (size_t)N * 50 * 4, stream);
        edge_pass_k<<<cdiv(Etot, 4), 256, 0, stream>>>(
            el, E, etype, tin, Etot, s1, s2, srel,
            x1A2, OD, q * 50, rpf, OD, q * 50, rowsum, q == 0 ? 1 : 0, accX2);
        combine50_k<<<cdiv(N * 50, 256), 256, 0, stream>>>(
            out_ent, q * 50, accX2, rowsum, out_mask, N);
    }

    // E. out_ent += l2norm(ent) @ W_entities  (accumulate)
    gemm_mfma_k<false, true, float, float><<<dim3(cdiv(OD, BN), cdiv(N, BM)), 256, 0, stream>>>(
        ent, DD, nscale, W_ent, OD, 0, out_ent, OD, N, OD, DD);

    // F. in-place row l2norm of out_ent
    l2norm_rows_k<<<cdiv(N, 4), 256, 0, stream>>>(out_ent, N, OD);
}

// Round 6
// 1189.070 us; speedup vs baseline: 1.4329x; 1.2480x over previous
//
#include <hip/hip_runtime.h>
#include <hip/hip_bf16.h>
#include <math.h>

// SpKBGAT: N=50000, D=200, R=500, NHID=100, H=2, OD=200, E=150000, ENH=30000.
// All I/O fp32. R6: row-block fused MFMA kernels (one block owns all output
// columns of its 64-row stripe -> A fetched once, rowdots + l2norm fused into
// epilogues); edge phase: per-edge weights precomputed, 100-wide scatters.
#define DD   200
#define NHID 100
#define OD   200
#define KPAD 48   // LDS row stride (bf16 elems); 96B, 16B-aligned

typedef __attribute__((ext_vector_type(8))) short short8;
typedef __attribute__((ext_vector_type(4))) float f32x4;

static inline int cdiv(int a, int b) { return (a + b - 1) / b; }

__device__ inline float toF(float x) { return x; }
__device__ inline float toF(__hip_bfloat16 x) { return __bfloat162float(x); }
__device__ inline void storeC(float v, float* p) { *p = v; }
__device__ inline void storeC(float v, __hip_bfloat16* p) { *p = __float2bfloat16(v); }

// -------- per-row inverse L2 norm (f32), wave per row --------
__global__ __launch_bounds__(256)
void rownorm_inv_k(const float* __restrict__ in, float* __restrict__ sc, int M, int Dd)
{
    int wave = (blockIdx.x * blockDim.x + threadIdx.x) >> 6;
    int lane = threadIdx.x & 63;
    if (wave >= M) return;
    float ss = 0.f;
    for (int k = lane; k < Dd; k += 64) {
        float x = in[(size_t)wave * Dd + k];
        ss += x * x;
    }
    for (int o = 32; o > 0; o >>= 1) ss += __shfl_down(ss, o);
    if (lane == 0) sc[wave] = 1.f / fmaxf(sqrtf(ss), 1e-12f);
}

// -------- generic MFMA GEMM (kept for small R-sized matmuls) --------
template<bool BTr, typename AT, typename CT>
__global__ __launch_bounds__(256)
void gemm_mfma_k(const AT* __restrict__ A, int lda, const float* __restrict__ ascale,
                 const float* __restrict__ B, int ldb, int colOff,
                 CT* __restrict__ C, int ldc, int M, int Nc, int K)
{
    __shared__ __align__(16) __hip_bfloat16 As[64][KPAD];
    __shared__ __align__(16) __hip_bfloat16 Bs[64][KPAD];
    int tid  = threadIdx.x;
    int wave = tid >> 6, lane = tid & 63;
    int quad = lane >> 4, l16 = lane & 15;
    int n0 = blockIdx.x * 64, m0 = blockIdx.y * 64;
    f32x4 acc[4];
#pragma unroll
    for (int t = 0; t < 4; t++) acc[t] = (f32x4){0.f, 0.f, 0.f, 0.f};

    for (int k0 = 0; k0 < K; k0 += 32) {
        {
            int m = tid >> 2, kc = (tid & 3) * 8;
            int gm = m0 + m;
            float scale = (ascale && gm < M) ? ascale[gm] : 1.f;
#pragma unroll
            for (int j = 0; j < 8; j++) {
                int gk = k0 + kc + j;
                float v = 0.f;
                if (gm < M && gk < K) v = toF(A[(size_t)gm * lda + gk]) * scale;
                As[m][kc + j] = __float2bfloat16(v);
            }
        }
        if (BTr) {
            int n = tid >> 2, kc = (tid & 3) * 8;
            int gn = n0 + n;
#pragma unroll
            for (int j = 0; j < 8; j++) {
                int gk = k0 + kc + j;
                float v = 0.f;
                if (gn < Nc && gk < K) v = B[(size_t)gn * ldb + colOff + gk];
                Bs[n][kc + j] = __float2bfloat16(v);
            }
        } else {
            int n = tid & 63, kq = tid >> 6;
            int gn = n0 + n;
#pragma unroll
            for (int j = 0; j < 8; j++) {
                int gk = k0 + kq * 8 + j;
                float v = 0.f;
                if (gn < Nc && gk < K) v = B[(size_t)gk * ldb + gn];
                Bs[n][kq * 8 + j] = __float2bfloat16(v);
            }
        }
        __syncthreads();
        short8 a = *(const short8*)&As[wave * 16 + l16][quad * 8];
#pragma unroll
        for (int t = 0; t < 4; t++) {
            short8 b = *(const short8*)&Bs[t * 16 + l16][quad * 8];
            acc[t] = __builtin_amdgcn_mfma_f32_16x16x32_bf16(a, b, acc[t], 0, 0, 0);
        }
        __syncthreads();
    }
#pragma unroll
    for (int t = 0; t < 4; t++) {
        int gn = n0 + t * 16 + l16;
        if (gn >= Nc) continue;
#pragma unroll
        for (int i = 0; i < 4; i++) {
            int gm = m0 + wave * 16 + quad * 4 + i;
            if (gm < M) storeC(acc[t][i], &C[(size_t)gm * ldc + gn]);
        }
    }
}

// -------- layer-1 fused projection (per head): Nc=200 (xa1|xa2) ----------
// Outputs: cols 0-99 -> x1[:, hoff..], cols 100-199 -> pBh[N,100].
// Fused s1 = xa1 . a2h, s2 = xa2 . a2h.
__global__ __launch_bounds__(256)
void l1_proj_k(const float* __restrict__ A, const float* __restrict__ nscale,
               const float* __restrict__ ah, const float* __restrict__ a2h,
               __hip_bfloat16* __restrict__ x1, int hoff,
               __hip_bfloat16* __restrict__ pBh,
               float* __restrict__ s1, float* __restrict__ s2, int M)
{
    __shared__ __align__(16) __hip_bfloat16 As[64][KPAD];
    __shared__ __align__(16) __hip_bfloat16 Bs[208][KPAD];
    int tid = threadIdx.x, wave = tid >> 6, lane = tid & 63;
    int quad = lane >> 4, l16 = lane & 15;
    int m0 = blockIdx.x * 64;
    f32x4 acc[13];
#pragma unroll
    for (int t = 0; t < 13; t++) acc[t] = (f32x4){0.f, 0.f, 0.f, 0.f};

    int mst = tid >> 2, kc = (tid & 3) * 8;
    for (int k0 = 0; k0 < DD; k0 += 32) {
        {
            int gm = m0 + mst;
            float sc = gm < M ? nscale[gm] : 0.f;
#pragma unroll
            for (int j = 0; j < 8; j++) {
                int gk = k0 + kc + j;
                float v = 0.f;
                if (gm < M && gk < DD) v = A[(size_t)gm * DD + gk] * sc;
                As[mst][kc + j] = __float2bfloat16(v);
            }
        }
#pragma unroll
        for (int r = 0; r < 4; r++) {
            int col = r * 64 + mst;
            if (col < 208) {
                const float* base = nullptr;
                if (col < 100) base = ah + (size_t)col * 600;
                else if (col < 200) base = ah + (size_t)(col - 100) * 600 + 200;
#pragma unroll
                for (int j = 0; j < 8; j++) {
                    int gk = k0 + kc + j;
                    float v = (base && gk < DD) ? base[gk] : 0.f;
                    Bs[col][kc + j] = __float2bfloat16(v);
                }
            }
        }
        __syncthreads();
        short8 a = *(const short8*)&As[wave * 16 + l16][quad * 8];
#pragma unroll
        for (int t = 0; t < 13; t++) {
            short8 b = *(const short8*)&Bs[t * 16 + l16][quad * 8];
            acc[t] = __builtin_amdgcn_mfma_f32_16x16x32_bf16(a, b, acc[t], 0, 0, 0);
        }
        __syncthreads();
    }
    float d1[4] = {0.f, 0.f, 0.f, 0.f}, d2[4] = {0.f, 0.f, 0.f, 0.f};
#pragma unroll
    for (int t = 0; t < 13; t++) {
        int gn = t * 16 + l16;
        float w1 = (gn < 100) ? a2h[gn] : 0.f;
        float w2 = (gn >= 100 && gn < 200) ? a2h[gn - 100] : 0.f;
#pragma unroll
        for (int i = 0; i < 4; i++) {
            int gm = m0 + wave * 16 + quad * 4 + i;
            float v = acc[t][i];
            d1[i] += v * w1;
            d2[i] += v * w2;
            if (gm < M) {
                if (gn < 100) x1[(size_t)gm * OD + hoff + gn] = __float2bfloat16(v);
                else if (gn < 200) pBh[(size_t)gm * 100 + gn - 100] = __float2bfloat16(v);
            }
        }
    }
#pragma unroll
    for (int msk = 1; msk < 16; msk <<= 1)
#pragma unroll
        for (int i = 0; i < 4; i++) {
            d1[i] += __shfl_xor(d1[i], msk);
            d2[i] += __shfl_xor(d2[i], msk);
        }
    if (l16 == 0)
#pragma unroll
        for (int i = 0; i < 4; i++) {
            int gm = m0 + wave * 16 + quad * 4 + i;
            if (gm < M) { s1[gm] = d1[i]; s2[gm] = d2[i]; }
        }
}

// -------- layer-2 fused projection: Nc=400 (x1A1|x1A2) -------------------
// cols 0-199 -> x1A1 f32 (out_ent region), cols 200-399 -> x1A2 bf16.
// Fused s1 = x1A1 . a2o, s2 = x1A2 . a2o.
__global__ __launch_bounds__(256)
void l2_proj_k(const __hip_bfloat16* __restrict__ x1,
               const float* __restrict__ aout, const float* __restrict__ a2o,
               float* __restrict__ x1A1, __hip_bfloat16* __restrict__ x1A2,
               float* __restrict__ s1, float* __restrict__ s2, int M)
{
    __shared__ __align__(16) __hip_bfloat16 As[64][KPAD];
    __shared__ __align__(16) __hip_bfloat16 Bs[400][KPAD];
    int tid = threadIdx.x, wave = tid >> 6, lane = tid & 63;
    int quad = lane >> 4, l16 = lane & 15;
    int m0 = blockIdx.x * 64;
    f32x4 acc[25];
#pragma unroll
    for (int t = 0; t < 25; t++) acc[t] = (f32x4){0.f, 0.f, 0.f, 0.f};

    int mst = tid >> 2, kc = (tid & 3) * 8;
    for (int k0 = 0; k0 < OD; k0 += 32) {
        {
            int gm = m0 + mst;
#pragma unroll
            for (int j = 0; j < 8; j++) {
                int gk = k0 + kc + j;
                __hip_bfloat16 v = __float2bfloat16(0.f);
                if (gm < M && gk < OD) v = x1[(size_t)gm * OD + gk];
                As[mst][kc + j] = v;
            }
        }
#pragma unroll
        for (int r = 0; r < 7; r++) {
            int col = r * 64 + mst;
            if (col < 400) {
                const float* base = (col < 200) ? (aout + (size_t)col * 600)
                                                : (aout + (size_t)(col - 200) * 600 + 200);
#pragma unroll
                for (int j = 0; j < 8; j++) {
                    int gk = k0 + kc + j;
                    float v = (gk < OD) ? base[gk] : 0.f;
                    Bs[col][kc + j] = __float2bfloat16(v);
                }
            }
        }
        __syncthreads();
        short8 a = *(const short8*)&As[wave * 16 + l16][quad * 8];
#pragma unroll
        for (int t = 0; t < 25; t++) {
            short8 b = *(const short8*)&Bs[t * 16 + l16][quad * 8];
            acc[t] = __builtin_amdgcn_mfma_f32_16x16x32_bf16(a, b, acc[t], 0, 0, 0);
        }
        __syncthreads();
    }
    float d1[4] = {0.f, 0.f, 0.f, 0.f}, d2[4] = {0.f, 0.f, 0.f, 0.f};
#pragma unroll
    for (int t = 0; t < 25; t++) {
        int gn = t * 16 + l16;
        float w1 = (gn < 200) ? a2o[gn] : 0.f;
        float w2 = (gn >= 200) ? a2o[gn - 200] : 0.f;
#pragma unroll
        for (int i = 0; i < 4; i++) {
            int gm = m0 + wave * 16 + quad * 4 + i;
            float v = acc[t][i];
            d1[i] += v * w1;
            d2[i] += v * w2;
            if (gm < M) {
                if (gn < 200) x1A1[(size_t)gm * OD + gn] = v;
                else          x1A2[(size_t)gm * OD + gn - 200] = __float2bfloat16(v);
            }
        }
    }
#pragma unroll
    for (int msk = 1; msk < 16; msk <<= 1)
#pragma unroll
        for (int i = 0; i < 4; i++) {
            d1[i] += __shfl_xor(d1[i], msk);
            d2[i] += __shfl_xor(d2[i], msk);
        }
    if (l16 == 0)
#pragma unroll
        for (int i = 0; i < 4; i++) {
            int gm = m0 + wave * 16 + quad * 4 + i;
            if (gm < M) { s1[gm] = d1[i]; s2[gm] = d2[i]; }
        }
}

// -------- final: out_ent = l2norm(out_ent + (ent*nscale) @ W_ent) --------
__global__ __launch_bounds__(256)
void final_k(const float* __restrict__ ent, const float* __restrict__ nscale,
             const float* __restrict__ Went, float* __restrict__ outent, int M)
{
    __shared__ __align__(16) __hip_bfloat16 As[64][KPAD];
    __shared__ __align__(16) __hip_bfloat16 Bs[208][KPAD];
    int tid = threadIdx.x, wave = tid >> 6, lane = tid & 63;
    int quad = lane >> 4, l16 = lane & 15;
    int m0 = blockIdx.x * 64;
    f32x4 acc[13];
#pragma unroll
    for (int t = 0; t < 13; t++) acc[t] = (f32x4){0.f, 0.f, 0.f, 0.f};

    int mst = tid >> 2, kc = (tid & 3) * 8;
    for (int k0 = 0; k0 < DD; k0 += 32) {
        {
            int gm = m0 + mst;
            float sc = gm < M ? nscale[gm] : 0.f;
#pragma unroll
            for (int j = 0; j < 8; j++) {
                int gk = k0 + kc + j;
                float v = 0.f;
                if (gm < M && gk < DD) v = ent[(size_t)gm * DD + gk] * sc;
                As[mst][kc + j] = __float2bfloat16(v);
            }
        }
#pragma unroll
        for (int r = 0; r < 4; r++) {
            int n = r * 64 + (tid & 63);
            int kq = tid >> 6;
            if (n < 208) {
#pragma unroll
                for (int j = 0; j < 8; j++) {
                    int gk = k0 + kq * 8 + j;
                    float v = (n < OD && gk < DD) ? Went[(size_t)gk * OD + n] : 0.f;
                    Bs[n][kq * 8 + j] = __float2bfloat16(v);
                }
            }
        }
        __syncthreads();
        short8 a = *(const short8*)&As[wave * 16 + l16][quad * 8];
#pragma unroll
        for (int t = 0; t < 13; t++) {
            short8 b = *(const short8*)&Bs[t * 16 + l16][quad * 8];
            acc[t] = __builtin_amdgcn_mfma_f32_16x16x32_bf16(a, b, acc[t], 0, 0, 0);
        }
        __syncthreads();
    }
    float ss[4] = {0.f, 0.f, 0.f, 0.f};
#pragma unroll
    for (int t = 0; t < 13; t++) {
        int gn = t * 16 + l16;
#pragma unroll
        for (int i = 0; i < 4; i++) {
            int gm = m0 + wave * 16 + quad * 4 + i;
            float v = 0.f;
            if (gn < OD && gm < M) v = acc[t][i] + outent[(size_t)gm * OD + gn];
            acc[t][i] = v;
            ss[i] += v * v;
        }
    }
#pragma unroll
    for (int msk = 1; msk < 16; msk <<= 1)
#pragma unroll
        for (int i = 0; i < 4; i++) ss[i] += __shfl_xor(ss[i], msk);
    float scl[4];
#pragma unroll
    for (int i = 0; i < 4; i++) scl[i] = 1.f / fmaxf(sqrtf(ss[i]), 1e-12f);
#pragma unroll
    for (int t = 0; t < 13; t++) {
        int gn = t * 16 + l16;
        if (gn >= OD) continue;
#pragma unroll
        for (int i = 0; i < 4; i++) {
            int gm = m0 + wave * 16 + quad * 4 + i;
            if (gm < M) outent[(size_t)gm * OD + gn] = acc[t][i] * scl[i];
        }
    }
}

// -------- row-dot (small matrices: srel) --------
template<typename T>
__global__ __launch_bounds__(256)
void rowdot_k(const T* __restrict__ mat, int ld, int coff,
              const float* __restrict__ vec,
              float* __restrict__ outp, int M, int Dd)
{
    int wave = (blockIdx.x * blockDim.x + threadIdx.x) >> 6;
    int lane = threadIdx.x & 63;
    if (wave >= M) return;
    float s = 0.f;
    for (int k = lane; k < Dd; k += 64)
        s += toF(mat[(size_t)wave * ld + coff + k]) * vec[k];
    for (int o = 32; o > 0; o >>= 1) s += __shfl_down(s, o);
    if (lane == 0) outp[wave] = s;
}

// -------- per-edge attention weight + rowsum (thread per edge) --------
__global__ __launch_bounds__(256)
void edge_weight_k(const int* __restrict__ el, int E, const int* __restrict__ etype,
                   const int* __restrict__ tin, int Etot,
                   const float* __restrict__ s1, const float* __restrict__ s2,
                   const float* __restrict__ srel,
                   float* __restrict__ wedge, float* __restrict__ rowsum)
{
    int e = blockIdx.x * blockDim.x + threadIdx.x;
    if (e >= Etot) return;
    int dst, src, r1, r2;
    if (e < E) {
        dst = el[e]; src = el[E + e]; r1 = etype[e]; r2 = -1;
    } else {
        int j = e - E;
        dst = tin[j * 4 + 3]; src = tin[j * 4 + 0];
        r1 = tin[j * 4 + 1];  r2 = tin[j * 4 + 2];
    }
    float z = s1[dst] + s2[src] + srel[r1] + (r2 >= 0 ? srel[r2] : 0.f);
    float lz = z > 0.f ? z : 0.2f * z;
    float w = expf(-lz);
    wedge[e] = w;
    atomicAdd(&rowsum[dst], w);
}

// -------- edge scatter: 100 feature cols, wave per edge --------
__global__ __launch_bounds__(256)
void edge_scatter_k(const int* __restrict__ el, int E, const int* __restrict__ etype,
                    const int* __restrict__ tin, int Etot,
                    const float* __restrict__ wedge,
                    const __hip_bfloat16* __restrict__ xsrc, int xld, int xoff,
                    const float* __restrict__ rp, int rld, int roff,
                    float* __restrict__ acc)   // [N,100]
{
    int e = (blockIdx.x * blockDim.x + threadIdx.x) >> 6;
    int lane = threadIdx.x & 63;
    if (e >= Etot) return;
    int dst, src, r1, r2;
    if (e < E) {
        dst = el[e]; src = el[E + e]; r1 = etype[e]; r2 = -1;
    } else {
        int j = e - E;
        dst = tin[j * 4 + 3]; src = tin[j * 4 + 0];
        r1 = tin[j * 4 + 1];  r2 = tin[j * 4 + 2];
    }
    float w = wedge[e];
    const __hip_bfloat16* xs = xsrc + (size_t)src * xld + xoff;
    const float* rp1 = rp + (size_t)r1 * rld + roff;
    const float* rp2 = (r2 >= 0) ? (rp + (size_t)r2 * rld + roff) : rp1;
    for (int k = lane; k < 100; k += 64) {
        float v = __bfloat162float(xs[k]) + rp1[k] + (r2 >= 0 ? rp2[k] : 0.f);
        atomicAdd(&acc[(size_t)dst * 100 + k], w * v);
    }
}

// -------- layer-1 finalize: x1 slice = elu(x1 + acc/rs) --------
__global__ void finalize100_k(__hip_bfloat16* __restrict__ x1, int coff,
                              const float* __restrict__ acc,
                              const float* __restrict__ rowsum, int N)
{
    int i = blockIdx.x * blockDim.x + threadIdx.x;
    if (i >= N * 100) return;
    int n = i / 100, k = i - n * 100;
    size_t idx = (size_t)n * OD + coff + k;
    float rs = rowsum[n];
    float hp = rs > 0.f ? __bfloat162float(x1[idx]) + acc[i] / rs : 0.f;
    float e = hp > 0.f ? hp : expf(hp) - 1.f;
    x1[idx] = __float2bfloat16(e);
}

// -------- layer-2 combine (in place on f32 out_ent holding x1A1) --------
__global__ void combine100_k(float* __restrict__ outent, int coff,
                             const float* __restrict__ acc,
                             const float* __restrict__ rowsum,
                             const float* __restrict__ maskf, int N)
{
    int i = blockIdx.x * blockDim.x + threadIdx.x;
    if (i >= N * 100) return;
    int n = i / 100, k = i - n * 100;
    size_t idx = (size_t)n * OD + coff + k;
    float rs = rowsum[n];
    float hp = rs > 0.f ? outent[idx] + acc[i] / rs : 0.f;
    float e = hp > 0.f ? hp : expf(hp) - 1.f;
    outent[idx] = maskf[n] * e;
}

__global__ void scatter_mask_k(const int* __restrict__ batch, int NB,
                               float* __restrict__ masko)
{
    int i = blockIdx.x * blockDim.x + threadIdx.x;
    if (i >= NB) return;
    masko[batch[i]] = 1.0f;
}

extern "C" void kernel_launch(void* const* d_in, const int* in_sizes, int n_in,
                              void* d_out, int out_size, void* d_ws, size_t ws_size,
                              hipStream_t stream)
{
    const float* ent      = (const float*)d_in[0];
    const float* rel      = (const float*)d_in[1];
    const float* W_ent    = (const float*)d_in[2];
    const float* W_gat    = (const float*)d_in[3];
    const float* a_heads  = (const float*)d_in[4];
    const float* a2_heads = (const float*)d_in[5];
    const float* a_out    = (const float*)d_in[6];
    const float* a2_out   = (const float*)d_in[7];
    const int* batch = (const int*)d_in[8];
    const int* el    = (const int*)d_in[9];
    const int* etype = (const int*)d_in[10];
    const int* tin   = (const int*)d_in[11];

    const int N   = in_sizes[0] / DD;   // 50000
    const int R   = in_sizes[1] / DD;   // 500
    const int NB  = in_sizes[8];        // 20000
    const int E   = in_sizes[9] / 2;    // 150000
    const int ENH = in_sizes[11] / 4;   // 30000
    const int Etot = E + ENH;

    // ---- workspace (~42 MB) ----
    char* ws = (char*)d_ws;
    size_t off = 0;
    auto take = [&](size_t bytes) { size_t o = off; off += (bytes + 255) & ~(size_t)255; return o; };
    size_t o_R1   = take((size_t)N * OD * 2);  // x1 bf16 [N,200]; later accX2 f32 [N,100]
    size_t o_R2   = take((size_t)N * OD * 2);  // pBh bf16 [N,100] (half); later x1A2 bf16 [N,200]
    size_t o_rpf  = take((size_t)R * OD * 4);  // f32 relation projections
    size_t o_nsc  = take((size_t)N * 4);
    size_t o_s1   = take((size_t)N * 4);
    size_t o_s2   = take((size_t)N * 4);
    size_t o_rows = take((size_t)N * 4);
    size_t o_srel = take((size_t)R * 4);
    size_t o_wdg  = take((size_t)Etot * 4);

    __hip_bfloat16* x1    = (__hip_bfloat16*)(ws + o_R1);
    float*          accX2 = (float*)(ws + o_R1);          // after x1 dead
    __hip_bfloat16* pBh   = (__hip_bfloat16*)(ws + o_R2); // [N,100]
    __hip_bfloat16* x1A2  = (__hip_bfloat16*)(ws + o_R2); // [N,200] after pBh dead
    float* rpf    = (float*)(ws + o_rpf);
    float* nscale = (float*)(ws + o_nsc);
    float* s1     = (float*)(ws + o_s1);
    float* s2     = (float*)(ws + o_s2);
    float* rowsum = (float*)(ws + o_rows);
    float* srel   = (float*)(ws + o_srel);
    float* wedge  = (float*)(ws + o_wdg);

    float* out       = (float*)d_out;
    float* out_ent   = out;                                     // [N,200]
    float* out_rel_o = out + (size_t)N * OD;                    // [500,200]
    float* out_mask  = out + (size_t)N * OD + (size_t)R * OD;   // [N]
    float* accL1     = out_ent;                                 // [N,100] f32 scratch, phase B only

    const int nblk = cdiv(N, 64);

    // A. norms; out_rel = rel @ W_gat
    rownorm_inv_k<<<cdiv(N, 4), 256, 0, stream>>>(ent, nscale, N, DD);
    gemm_mfma_k<false, float, float><<<dim3(cdiv(OD, 64), cdiv(R, 64)), 256, 0, stream>>>(
        rel, DD, nullptr, W_gat, OD, 0, out_rel_o, OD, R, OD, DD);

    // B. layer-1 per head
    for (int h = 0; h < 2; h++) {
        const float* ah  = a_heads + (size_t)h * NHID * 600;
        const float* a2h = a2_heads + (size_t)h * NHID;
        l1_proj_k<<<nblk, 256, 0, stream>>>(ent, nscale, ah, a2h, x1, h * NHID, pBh, s1, s2, N);
        gemm_mfma_k<true, float, float><<<dim3(cdiv(NHID, 64), cdiv(R, 64)), 256, 0, stream>>>(
            rel, DD, nullptr, ah, 600, 400, rpf, NHID, R, NHID, DD);
        rowdot_k<float><<<cdiv(R, 4), 256, 0, stream>>>(rpf, NHID, 0, a2h, srel, R, NHID);
        hipMemsetAsync(rowsum, 0, (size_t)N * 4, stream);
        edge_weight_k<<<cdiv(Etot, 256), 256, 0, stream>>>(
            el, E, etype, tin, Etot, s1, s2, srel, wedge, rowsum);
        hipMemsetAsync(accL1, 0, (size_t)N * 100 * 4, stream);
        edge_scatter_k<<<cdiv(Etot, 4), 256, 0, stream>>>(
            el, E, etype, tin, Etot, wedge, pBh, NHID, 0, rpf, NHID, 0, accL1);
        finalize100_k<<<cdiv(N * 100, 256), 256, 0, stream>>>(x1, h * NHID, accL1, rowsum, N);
    }
    // pBh dead; R2 becomes x1A2.

    // C. layer-2 projections (x1A1 -> out_ent f32; x1A2 -> R2) + logits
    l2_proj_k<<<nblk, 256, 0, stream>>>(x1, a_out, a2_out, out_ent, x1A2, s1, s2, N);
    gemm_mfma_k<true, float, float><<<dim3(cdiv(OD, 64), cdiv(R, 64)), 256, 0, stream>>>(
        out_rel_o, OD, nullptr, a_out, 600, 400, rpf, OD, R, OD, OD);
    rowdot_k<float><<<cdiv(R, 4), 256, 0, stream>>>(rpf, OD, 0, a2_out, srel, R, OD);
    hipMemsetAsync(rowsum, 0, (size_t)N * 4, stream);
    edge_weight_k<<<cdiv(Etot, 256), 256, 0, stream>>>(
        el, E, etype, tin, Etot, s1, s2, srel, wedge, rowsum);
    // x1 dead; R1 becomes accX2.

    // D. mask; layer-2 aggregation in 2 halves; combine in place
    hipMemsetAsync(out_mask, 0, (size_t)N * 4, stream);
    scatter_mask_k<<<cdiv(NB, 256), 256, 0, stream>>>(batch, NB, out_mask);
    for (int q = 0; q < 2; q++) {
        hipMemsetAsync(accX2, 0, (size_t)N * 100 * 4, stream);
        edge_scatter_k<<<cdiv(Etot, 4), 256, 0, stream>>>(
            el, E, etype, tin, Etot, wedge, x1A2, OD, q * 100, rpf, OD, q * 100, accX2);
        combine100_k<<<cdiv(N * 100, 256), 256, 0, stream>>>(
            out_ent, q * 100, accX2, rowsum, out_mask, N);
    }

    // E. out_ent = l2norm(out_ent + (ent*nscale) @ W_ent)  (fused)
    final_k<<<nblk, 256, 0, stream>>>(ent, nscale, W_ent, out_ent, N);
}

// Round 7
// 886.875 us; speedup vs baseline: 1.9211x; 1.3407x over previous
//
#include <hip/hip_runtime.h>
#include <hip/hip_bf16.h>
#include <math.h>

// SpKBGAT: N=50000, D=200, R=500, NHID=100, H=2, OD=200, E=150000, ENH=30000.
// R7: big fused kernels are LDS-free / barrier-free register MFMA pipelines.
// B panels pre-converted to bf16 [col][KP] (zero-padded K->224); A fragments
// loaded straight from global (f32*nscale -> bf16 in-reg, or raw bf16).
#define DD   200
#define NHID 100
#define OD   200
#define KP   224   // padded K (7 chunks of 32)

typedef __attribute__((ext_vector_type(8))) short short8;
typedef __attribute__((ext_vector_type(4))) float f32x4;

static inline int cdiv(int a, int b) { return (a + b - 1) / b; }

__device__ inline float toF(float x) { return x; }
__device__ inline float toF(__hip_bfloat16 x) { return __bfloat162float(x); }
__device__ inline void storeC(float v, float* p) { *p = v; }
__device__ inline void storeC(float v, __hip_bfloat16* p) { *p = __float2bfloat16(v); }
__device__ inline short bf16s(float f) {
    __hip_bfloat16 h = __float2bfloat16(f);
    short s; __builtin_memcpy(&s, &h, 2); return s;
}

// -------- per-row inverse L2 norm (f32), wave per row --------
__global__ __launch_bounds__(256)
void rownorm_inv_k(const float* __restrict__ in, float* __restrict__ sc, int M, int Dd)
{
    int wave = (blockIdx.x * blockDim.x + threadIdx.x) >> 6;
    int lane = threadIdx.x & 63;
    if (wave >= M) return;
    float ss = 0.f;
    for (int k = lane; k < Dd; k += 64) {
        float x = in[(size_t)wave * Dd + k];
        ss += x * x;
    }
    for (int o = 32; o > 0; o >>= 1) ss += __shfl_down(ss, o);
    if (lane == 0) sc[wave] = 1.f / fmaxf(sqrtf(ss), 1e-12f);
}

// -------- B-panel prep: bf16 [col][KP], zero-padded --------
// l1: cols 0-99: ah0 row c (off 0)   | 100-199: ah1 row c-100 (off 0)
//     200-299: ah0 row c-200 (off200)| 300-399: ah1 row c-300 (off 200)
__global__ void prep_bt_l1(const float* __restrict__ ah, __hip_bfloat16* __restrict__ Bt)
{
    int c = blockIdx.x, k = threadIdx.x;
    if (k >= KP) return;
    int seg = c / 100, idx = c - seg * 100;
    int h = seg & 1, off = (seg >> 1) * 200;
    float v = (k < 200) ? ah[(size_t)(h * 100 + idx) * 600 + off + k] : 0.f;
    Bt[(size_t)c * KP + k] = __float2bfloat16(v);
}
// l2: cols 0-199: a_out row c off 0 | 200-399: a_out row c-200 off 200
__global__ void prep_bt_l2(const float* __restrict__ ao, __hip_bfloat16* __restrict__ Bt)
{
    int c = blockIdx.x, k = threadIdx.x;
    if (k >= KP) return;
    int row = (c < 200) ? c : c - 200;
    int off = (c < 200) ? 0 : 200;
    float v = (k < 200) ? ao[(size_t)row * 600 + off + k] : 0.f;
    Bt[(size_t)c * KP + k] = __float2bfloat16(v);
}
// fin: cols 0-199: W_ent^T (Bt[c][k] = Went[k*200+c]); 200-207 zero
__global__ void prep_bt_fin(const float* __restrict__ W, __hip_bfloat16* __restrict__ Bt)
{
    int c = blockIdx.x, k = threadIdx.x;
    if (k >= KP) return;
    float v = (c < 200 && k < 200) ? W[(size_t)k * 200 + c] : 0.f;
    Bt[(size_t)c * KP + k] = __float2bfloat16(v);
}

// -------- layer-1 fused (both heads): 25 tiles = xa1_h0|xa1_h1|xa2_h0|xa2_h1
__global__ __launch_bounds__(256)
void l1_both_k(const float* __restrict__ ent, const float* __restrict__ nscale,
               const __hip_bfloat16* __restrict__ Bt,  // [400][KP]
               const float* __restrict__ a2h,          // [2][100]
               __hip_bfloat16* __restrict__ x1,        // [N][KP] (cols 0-199)
               __hip_bfloat16* __restrict__ pB,        // [2][N][100]
               float* __restrict__ s1, float* __restrict__ s2,  // [2][N]
               int M, size_t PN)
{
    int tid = threadIdx.x, wave = tid >> 6, lane = tid & 63;
    int quad = lane >> 4, l16 = lane & 15;
    int m0 = blockIdx.x * 64;
    int arow = m0 + wave * 16 + l16;
    bool rok = arow < M;
    float nsc = rok ? nscale[arow] : 0.f;
    const float* arp = ent + (size_t)arow * DD;

    f32x4 acc[25];
#pragma unroll
    for (int t = 0; t < 25; t++) acc[t] = (f32x4){0.f, 0.f, 0.f, 0.f};

    for (int ch = 0; ch < 7; ch++) {
        int kb = ch * 32 + quad * 8;
        float av[8];
        if (rok && kb + 8 <= DD) {
            const float4* p = (const float4*)(arp + kb);
            float4 u0 = p[0], u1 = p[1];
            av[0] = u0.x; av[1] = u0.y; av[2] = u0.z; av[3] = u0.w;
            av[4] = u1.x; av[5] = u1.y; av[6] = u1.z; av[7] = u1.w;
        } else {
#pragma unroll
            for (int j = 0; j < 8; j++) av[j] = (rok && kb + j < DD) ? arp[kb + j] : 0.f;
        }
        short8 a;
#pragma unroll
        for (int j = 0; j < 8; j++) a[j] = bf16s(av[j] * nsc);
        const __hip_bfloat16* bp = Bt + (size_t)l16 * KP + kb;
#pragma unroll
        for (int t = 0; t < 25; t++) {
            short8 b = *(const short8*)(bp + (size_t)t * 16 * KP);
            acc[t] = __builtin_amdgcn_mfma_f32_16x16x32_bf16(a, b, acc[t], 0, 0, 0);
        }
    }

    int orow = m0 + wave * 16 + quad * 4;
    float d0[4] = {0,0,0,0}, d1[4] = {0,0,0,0}, d2[4] = {0,0,0,0}, d3[4] = {0,0,0,0};
#pragma unroll
    for (int t = 0; t < 25; t++) {
        int c = t * 16 + l16;
        int seg = c / 100, idx = c - seg * 100;
        float w = a2h[(seg & 1) * 100 + idx];
#pragma unroll
        for (int i = 0; i < 4; i++) {
            float v = acc[t][i];
            float vw = v * w;
            if (seg == 0) d0[i] += vw;
            else if (seg == 1) d1[i] += vw;
            else if (seg == 2) d2[i] += vw;
            else d3[i] += vw;
            int gm = orow + i;
            if (gm < M) {
                if (seg < 2) x1[(size_t)gm * KP + c] = __float2bfloat16(v);
                else pB[(size_t)(seg - 2) * PN + (size_t)gm * 100 + idx] = __float2bfloat16(v);
            }
        }
    }
#pragma unroll
    for (int msk = 1; msk < 16; msk <<= 1)
#pragma unroll
        for (int i = 0; i < 4; i++) {
            d0[i] += __shfl_xor(d0[i], msk);
            d1[i] += __shfl_xor(d1[i], msk);
            d2[i] += __shfl_xor(d2[i], msk);
            d3[i] += __shfl_xor(d3[i], msk);
        }
    if (l16 == 0)
#pragma unroll
        for (int i = 0; i < 4; i++) {
            int gm = orow + i;
            if (gm < M) {
                s1[gm] = d0[i]; s1[M + gm] = d1[i];
                s2[gm] = d2[i]; s2[M + gm] = d3[i];
            }
        }
}

// -------- layer-2 fused: 25 tiles = x1A1 (f32 -> out_ent) | x1A2 (bf16) ----
__global__ __launch_bounds__(256)
void l2_proj_k(const __hip_bfloat16* __restrict__ x1,  // [N][KP]
               const __hip_bfloat16* __restrict__ Bt,  // [400][KP]
               const float* __restrict__ a2o,          // [200]
               float* __restrict__ x1A1,               // [N][200] (out_ent)
               __hip_bfloat16* __restrict__ x1A2,      // [N][200]
               float* __restrict__ s1, float* __restrict__ s2, int M)
{
    int tid = threadIdx.x, wave = tid >> 6, lane = tid & 63;
    int quad = lane >> 4, l16 = lane & 15;
    int m0 = blockIdx.x * 64;
    int arow = m0 + wave * 16 + l16;
    bool rok = arow < M;
    const __hip_bfloat16* arp = x1 + (size_t)arow * KP;

    f32x4 acc[25];
#pragma unroll
    for (int t = 0; t < 25; t++) acc[t] = (f32x4){0.f, 0.f, 0.f, 0.f};

    for (int ch = 0; ch < 7; ch++) {
        int kb = ch * 32 + quad * 8;
        short8 a = (short8){0,0,0,0,0,0,0,0};
        if (rok) a = *(const short8*)(arp + kb);
        const __hip_bfloat16* bp = Bt + (size_t)l16 * KP + kb;
#pragma unroll
        for (int t = 0; t < 25; t++) {
            short8 b = *(const short8*)(bp + (size_t)t * 16 * KP);
            acc[t] = __builtin_amdgcn_mfma_f32_16x16x32_bf16(a, b, acc[t], 0, 0, 0);
        }
    }

    int orow = m0 + wave * 16 + quad * 4;
    float dA[4] = {0,0,0,0}, dB[4] = {0,0,0,0};
#pragma unroll
    for (int t = 0; t < 25; t++) {
        int c = t * 16 + l16;
        bool first = c < 200;
        int cc = first ? c : c - 200;
        float w = a2o[cc];
#pragma unroll
        for (int i = 0; i < 4; i++) {
            float v = acc[t][i];
            int gm = orow + i;
            if (first) {
                dA[i] += v * w;
                if (gm < M) x1A1[(size_t)gm * OD + c] = v;
            } else {
                dB[i] += v * w;
                if (gm < M) x1A2[(size_t)gm * OD + cc] = __float2bfloat16(v);
            }
        }
    }
#pragma unroll
    for (int msk = 1; msk < 16; msk <<= 1)
#pragma unroll
        for (int i = 0; i < 4; i++) {
            dA[i] += __shfl_xor(dA[i], msk);
            dB[i] += __shfl_xor(dB[i], msk);
        }
    if (l16 == 0)
#pragma unroll
        for (int i = 0; i < 4; i++) {
            int gm = orow + i;
            if (gm < M) { s1[gm] = dA[i]; s2[gm] = dB[i]; }
        }
}

// -------- final: out_ent = l2norm(out_ent + (ent*nscale) @ W_ent) ---------
__global__ __launch_bounds__(256)
void final_mfma_k(const float* __restrict__ ent, const float* __restrict__ nscale,
                  const __hip_bfloat16* __restrict__ Bt,  // [208][KP]
                  float* __restrict__ outent, int M)
{
    int tid = threadIdx.x, wave = tid >> 6, lane = tid & 63;
    int quad = lane >> 4, l16 = lane & 15;
    int m0 = blockIdx.x * 64;
    int arow = m0 + wave * 16 + l16;
    bool rok = arow < M;
    float nsc = rok ? nscale[arow] : 0.f;
    const float* arp = ent + (size_t)arow * DD;

    f32x4 acc[13];
#pragma unroll
    for (int t = 0; t < 13; t++) acc[t] = (f32x4){0.f, 0.f, 0.f, 0.f};

    for (int ch = 0; ch < 7; ch++) {
        int kb = ch * 32 + quad * 8;
        float av[8];
        if (rok && kb + 8 <= DD) {
            const float4* p = (const float4*)(arp + kb);
            float4 u0 = p[0], u1 = p[1];
            av[0] = u0.x; av[1] = u0.y; av[2] = u0.z; av[3] = u0.w;
            av[4] = u1.x; av[5] = u1.y; av[6] = u1.z; av[7] = u1.w;
        } else {
#pragma unroll
            for (int j = 0; j < 8; j++) av[j] = (rok && kb + j < DD) ? arp[kb + j] : 0.f;
        }
        short8 a;
#pragma unroll
        for (int j = 0; j < 8; j++) a[j] = bf16s(av[j] * nsc);
        const __hip_bfloat16* bp = Bt + (size_t)l16 * KP + kb;
#pragma unroll
        for (int t = 0; t < 13; t++) {
            short8 b = *(const short8*)(bp + (size_t)t * 16 * KP);
            acc[t] = __builtin_amdgcn_mfma_f32_16x16x32_bf16(a, b, acc[t], 0, 0, 0);
        }
    }

    int orow = m0 + wave * 16 + quad * 4;
    float ss[4] = {0.f, 0.f, 0.f, 0.f};
#pragma unroll
    for (int t = 0; t < 13; t++) {
        int gn = t * 16 + l16;
#pragma unroll
        for (int i = 0; i < 4; i++) {
            int gm = orow + i;
            float v = 0.f;
            if (gn < OD && gm < M) v = acc[t][i] + outent[(size_t)gm * OD + gn];
            acc[t][i] = v;
            ss[i] += v * v;
        }
    }
#pragma unroll
    for (int msk = 1; msk < 16; msk <<= 1)
#pragma unroll
        for (int i = 0; i < 4; i++) ss[i] += __shfl_xor(ss[i], msk);
    float scl[4];
#pragma unroll
    for (int i = 0; i < 4; i++) scl[i] = 1.f / fmaxf(sqrtf(ss[i]), 1e-12f);
#pragma unroll
    for (int t = 0; t < 13; t++) {
        int gn = t * 16 + l16;
        if (gn >= OD) continue;
#pragma unroll
        for (int i = 0; i < 4; i++) {
            int gm = orow + i;
            if (gm < M) outent[(size_t)gm * OD + gn] = acc[t][i] * scl[i];
        }
    }
}

// -------- generic MFMA GEMM (small R-sized matmuls) --------
#define KPAD 48
template<bool BTr, typename AT, typename CT>
__global__ __launch_bounds__(256)
void gemm_mfma_k(const AT* __restrict__ A, int lda, const float* __restrict__ ascale,
                 const float* __restrict__ B, int ldb, int colOff,
                 CT* __restrict__ C, int ldc, int M, int Nc, int K)
{
    __shared__ __align__(16) __hip_bfloat16 As[64][KPAD];
    __shared__ __align__(16) __hip_bfloat16 Bs[64][KPAD];
    int tid  = threadIdx.x;
    int wave = tid >> 6, lane = tid & 63;
    int quad = lane >> 4, l16 = lane & 15;
    int n0 = blockIdx.x * 64, m0 = blockIdx.y * 64;
    f32x4 acc[4];
#pragma unroll
    for (int t = 0; t < 4; t++) acc[t] = (f32x4){0.f, 0.f, 0.f, 0.f};

    for (int k0 = 0; k0 < K; k0 += 32) {
        {
            int m = tid >> 2, kc = (tid & 3) * 8;
            int gm = m0 + m;
            float scale = (ascale && gm < M) ? ascale[gm] : 1.f;
#pragma unroll
            for (int j = 0; j < 8; j++) {
                int gk = k0 + kc + j;
                float v = 0.f;
                if (gm < M && gk < K) v = toF(A[(size_t)gm * lda + gk]) * scale;
                As[m][kc + j] = __float2bfloat16(v);
            }
        }
        if (BTr) {
            int n = tid >> 2, kc = (tid & 3) * 8;
            int gn = n0 + n;
#pragma unroll
            for (int j = 0; j < 8; j++) {
                int gk = k0 + kc + j;
                float v = 0.f;
                if (gn < Nc && gk < K) v = B[(size_t)gn * ldb + colOff + gk];
                Bs[n][kc + j] = __float2bfloat16(v);
            }
        } else {
            int n = tid & 63, kq = tid >> 6;
            int gn = n0 + n;
#pragma unroll
            for (int j = 0; j < 8; j++) {
                int gk = k0 + kq * 8 + j;
                float v = 0.f;
                if (gn < Nc && gk < K) v = B[(size_t)gk * ldb + gn];
                Bs[n][kq * 8 + j] = __float2bfloat16(v);
            }
        }
        __syncthreads();
        short8 a = *(const short8*)&As[wave * 16 + l16][quad * 8];
#pragma unroll
        for (int t = 0; t < 4; t++) {
            short8 b = *(const short8*)&Bs[t * 16 + l16][quad * 8];
            acc[t] = __builtin_amdgcn_mfma_f32_16x16x32_bf16(a, b, acc[t], 0, 0, 0);
        }
        __syncthreads();
    }
#pragma unroll
    for (int t = 0; t < 4; t++) {
        int gn = n0 + t * 16 + l16;
        if (gn >= Nc) continue;
#pragma unroll
        for (int i = 0; i < 4; i++) {
            int gm = m0 + wave * 16 + quad * 4 + i;
            if (gm < M) storeC(acc[t][i], &C[(size_t)gm * ldc + gn]);
        }
    }
}

// -------- row-dot (srel) --------
template<typename T>
__global__ __launch_bounds__(256)
void rowdot_k(const T* __restrict__ mat, int ld, int coff,
              const float* __restrict__ vec,
              float* __restrict__ outp, int M, int Dd)
{
    int wave = (blockIdx.x * blockDim.x + threadIdx.x) >> 6;
    int lane = threadIdx.x & 63;
    if (wave >= M) return;
    float s = 0.f;
    for (int k = lane; k < Dd; k += 64)
        s += toF(mat[(size_t)wave * ld + coff + k]) * vec[k];
    for (int o = 32; o > 0; o >>= 1) s += __shfl_down(s, o);
    if (lane == 0) outp[wave] = s;
}

// -------- per-edge weight + rowsum --------
__global__ __launch_bounds__(256)
void edge_weight_k(const int* __restrict__ el, int E, const int* __restrict__ etype,
                   const int* __restrict__ tin, int Etot,
                   const float* __restrict__ s1, const float* __restrict__ s2,
                   const float* __restrict__ srel,
                   float* __restrict__ wedge, float* __restrict__ rowsum)
{
    int e = blockIdx.x * blockDim.x + threadIdx.x;
    if (e >= Etot) return;
    int dst, src, r1, r2;
    if (e < E) {
        dst = el[e]; src = el[E + e]; r1 = etype[e]; r2 = -1;
    } else {
        int j = e - E;
        dst = tin[j * 4 + 3]; src = tin[j * 4 + 0];
        r1 = tin[j * 4 + 1];  r2 = tin[j * 4 + 2];
    }
    float z = s1[dst] + s2[src] + srel[r1] + (r2 >= 0 ? srel[r2] : 0.f);
    float lz = z > 0.f ? z : 0.2f * z;
    float w = expf(-lz);
    wedge[e] = w;
    atomicAdd(&rowsum[dst], w);
}

// -------- edge scatter: 100 feature cols, wave per edge --------
__global__ __launch_bounds__(256)
void edge_scatter_k(const int* __restrict__ el, int E, const int* __restrict__ etype,
                    const int* __restrict__ tin, int Etot,
                    const float* __restrict__ wedge,
                    const __hip_bfloat16* __restrict__ xsrc, int xld, int xoff,
                    const float* __restrict__ rp, int rld, int roff,
                    float* __restrict__ acc)   // [N,100]
{
    int e = (blockIdx.x * blockDim.x + threadIdx.x) >> 6;
    int lane = threadIdx.x & 63;
    if (e >= Etot) return;
    int dst, src, r1, r2;
    if (e < E) {
        dst = el[e]; src = el[E + e]; r1 = etype[e]; r2 = -1;
    } else {
        int j = e - E;
        dst = tin[j * 4 + 3]; src = tin[j * 4 + 0];
        r1 = tin[j * 4 + 1];  r2 = tin[j * 4 + 2];
    }
    float w = wedge[e];
    const __hip_bfloat16* xs = xsrc + (size_t)src * xld + xoff;
    const float* rp1 = rp + (size_t)r1 * rld + roff;
    const float* rp2 = (r2 >= 0) ? (rp + (size_t)r2 * rld + roff) : rp1;
    for (int k = lane; k < 100; k += 64) {
        float v = __bfloat162float(xs[k]) + rp1[k] + (r2 >= 0 ? rp2[k] : 0.f);
        atomicAdd(&acc[(size_t)dst * 100 + k], w * v);
    }
}

// -------- layer-1 finalize: x1 slice = elu(x1 + acc/rs) --------
__global__ void finalize100_k(__hip_bfloat16* __restrict__ x1, int ld, int coff,
                              const float* __restrict__ acc,
                              const float* __restrict__ rowsum, int N)
{
    int i = blockIdx.x * blockDim.x + threadIdx.x;
    if (i >= N * 100) return;
    int n = i / 100, k = i - n * 100;
    size_t idx = (size_t)n * ld + coff + k;
    float rs = rowsum[n];
    float hp = rs > 0.f ? __bfloat162float(x1[idx]) + acc[i] / rs : 0.f;
    float e = hp > 0.f ? hp : expf(hp) - 1.f;
    x1[idx] = __float2bfloat16(e);
}

// -------- layer-2 combine (in place on f32 out_ent) --------
__global__ void combine100_k(float* __restrict__ outent, int coff,
                             const float* __restrict__ acc,
                             const float* __restrict__ rowsum,
                             const float* __restrict__ maskf, int N)
{
    int i = blockIdx.x * blockDim.x + threadIdx.x;
    if (i >= N * 100) return;
    int n = i / 100, k = i - n * 100;
    size_t idx = (size_t)n * OD + coff + k;
    float rs = rowsum[n];
    float hp = rs > 0.f ? outent[idx] + acc[i] / rs : 0.f;
    float e = hp > 0.f ? hp : expf(hp) - 1.f;
    outent[idx] = maskf[n] * e;
}

__global__ void scatter_mask_k(const int* __restrict__ batch, int NB,
                               float* __restrict__ masko)
{
    int i = blockIdx.x * blockDim.x + threadIdx.x;
    if (i >= NB) return;
    masko[batch[i]] = 1.0f;
}

extern "C" void kernel_launch(void* const* d_in, const int* in_sizes, int n_in,
                              void* d_out, int out_size, void* d_ws, size_t ws_size,
                              hipStream_t stream)
{
    const float* ent      = (const float*)d_in[0];
    const float* rel      = (const float*)d_in[1];
    const float* W_ent    = (const float*)d_in[2];
    const float* W_gat    = (const float*)d_in[3];
    const float* a_heads  = (const float*)d_in[4];
    const float* a2_heads = (const float*)d_in[5];
    const float* a_out    = (const float*)d_in[6];
    const float* a2_out   = (const float*)d_in[7];
    const int* batch = (const int*)d_in[8];
    const int* el    = (const int*)d_in[9];
    const int* etype = (const int*)d_in[10];
    const int* tin   = (const int*)d_in[11];

    const int N   = in_sizes[0] / DD;   // 50000
    const int R   = in_sizes[1] / DD;   // 500
    const int NB  = in_sizes[8];        // 20000
    const int E   = in_sizes[9] / 2;    // 150000
    const int ENH = in_sizes[11] / 4;   // 30000
    const int Etot = E + ENH;
    const size_t PN = (size_t)N * 100;

    // ---- workspace (~45.2 MB) ----
    char* ws = (char*)d_ws;
    size_t off = 0;
    auto take = [&](size_t bytes) { size_t o = off; off += (bytes + 255) & ~(size_t)255; return o; };
    size_t o_R1   = take((size_t)N * KP * 2);   // x1 bf16 [N][KP]; later accX2 f32 [N,100]
    size_t o_R2   = take((size_t)N * OD * 2);   // pB [2][N][100]; later x1A2 bf16 [N,200]
    size_t o_rpf  = take((size_t)R * OD * 4);   // relation projections f32
    size_t o_bt1  = take((size_t)400 * KP * 2);
    size_t o_bt2  = take((size_t)400 * KP * 2);
    size_t o_btf  = take((size_t)208 * KP * 2);
    size_t o_nsc  = take((size_t)N * 4);
    size_t o_s1   = take((size_t)2 * N * 4);
    size_t o_s2   = take((size_t)2 * N * 4);
    size_t o_rows = take((size_t)N * 4);
    size_t o_srel = take((size_t)R * 4);
    size_t o_wdg  = take((size_t)Etot * 4);

    __hip_bfloat16* x1    = (__hip_bfloat16*)(ws + o_R1);
    float*          accX2 = (float*)(ws + o_R1);          // after x1 dead
    __hip_bfloat16* pB    = (__hip_bfloat16*)(ws + o_R2); // [2][N][100]
    __hip_bfloat16* x1A2  = (__hip_bfloat16*)(ws + o_R2); // [N][200] after pB dead
    float* rpf    = (float*)(ws + o_rpf);
    __hip_bfloat16* bt1 = (__hip_bfloat16*)(ws + o_bt1);
    __hip_bfloat16* bt2 = (__hip_bfloat16*)(ws + o_bt2);
    __hip_bfloat16* btf = (__hip_bfloat16*)(ws + o_btf);
    float* nscale = (float*)(ws + o_nsc);
    float* s1     = (float*)(ws + o_s1);
    float* s2     = (float*)(ws + o_s2);
    float* rowsum = (float*)(ws + o_rows);
    float* srel   = (float*)(ws + o_srel);
    float* wedge  = (float*)(ws + o_wdg);

    float* out       = (float*)d_out;
    float* out_ent   = out;                                     // [N,200]
    float* out_rel_o = out + (size_t)N * OD;                    // [500,200]
    float* out_mask  = out + (size_t)N * OD + (size_t)R * OD;   // [N]
    float* accL1     = out_ent;                                 // [N,100] scratch (phase B)

    const int nblk = cdiv(N, 64);

    // A. prep: norms, B panels, x1 zero-pad; out_rel
    rownorm_inv_k<<<cdiv(N, 4), 256, 0, stream>>>(ent, nscale, N, DD);
    prep_bt_l1<<<400, 256, 0, stream>>>(a_heads, bt1);
    prep_bt_l2<<<400, 256, 0, stream>>>(a_out, bt2);
    prep_bt_fin<<<208, 256, 0, stream>>>(W_ent, btf);
    hipMemsetAsync(x1, 0, (size_t)N * KP * 2, stream);
    gemm_mfma_k<false, float, float><<<dim3(cdiv(OD, 64), cdiv(R, 64)), 256, 0, stream>>>(
        rel, DD, nullptr, W_gat, OD, 0, out_rel_o, OD, R, OD, DD);

    // B. layer-1 projections (both heads, fused) + per-head attention
    l1_both_k<<<nblk, 256, 0, stream>>>(ent, nscale, bt1, a2_heads, x1, pB, s1, s2, N, PN);
    for (int h = 0; h < 2; h++) {
        const float* ah  = a_heads + (size_t)h * NHID * 600;
        const float* a2h = a2_heads + (size_t)h * NHID;
        gemm_mfma_k<true, float, float><<<dim3(cdiv(NHID, 64), cdiv(R, 64)), 256, 0, stream>>>(
            rel, DD, nullptr, ah, 600, 400, rpf, NHID, R, NHID, DD);
        rowdot_k<float><<<cdiv(R, 4), 256, 0, stream>>>(rpf, NHID, 0, a2h, srel, R, NHID);
        hipMemsetAsync(rowsum, 0, (size_t)N * 4, stream);
        edge_weight_k<<<cdiv(Etot, 256), 256, 0, stream>>>(
            el, E, etype, tin, Etot, s1 + (size_t)h * N, s2 + (size_t)h * N, srel, wedge, rowsum);
        hipMemsetAsync(accL1, 0, (size_t)N * 100 * 4, stream);
        edge_scatter_k<<<cdiv(Etot, 4), 256, 0, stream>>>(
            el, E, etype, tin, Etot, wedge, pB + (size_t)h * PN, 100, 0, rpf, NHID, 0, accL1);
        finalize100_k<<<cdiv(N * 100, 256), 256, 0, stream>>>(x1, KP, h * 100, accL1, rowsum, N);
    }
    // pB dead; R2 becomes x1A2.

    // C. layer-2 projection (fused) + rel side
    l2_proj_k<<<nblk, 256, 0, stream>>>(x1, bt2, a2_out, out_ent, x1A2, s1, s2, N);
    gemm_mfma_k<true, float, float><<<dim3(cdiv(OD, 64), cdiv(R, 64)), 256, 0, stream>>>(
        out_rel_o, OD, nullptr, a_out, 600, 400, rpf, OD, R, OD, OD);
    rowdot_k<float><<<cdiv(R, 4), 256, 0, stream>>>(rpf, OD, 0, a2_out, srel, R, OD);
    hipMemsetAsync(rowsum, 0, (size_t)N * 4, stream);
    edge_weight_k<<<cdiv(Etot, 256), 256, 0, stream>>>(
        el, E, etype, tin, Etot, s1, s2, srel, wedge, rowsum);
    // x1 dead; R1 becomes accX2.

    // D. mask; layer-2 aggregation (2 halves); combine in place
    hipMemsetAsync(out_mask, 0, (size_t)N * 4, stream);
    scatter_mask_k<<<cdiv(NB, 256), 256, 0, stream>>>(batch, NB, out_mask);
    for (int q = 0; q < 2; q++) {
        hipMemsetAsync(accX2, 0, (size_t)N * 100 * 4, stream);
        edge_scatter_k<<<cdiv(Etot, 4), 256, 0, stream>>>(
            el, E, etype, tin, Etot, wedge, x1A2, OD, q * 100, rpf, OD, q * 100, accX2);
        combine100_k<<<cdiv(N * 100, 256), 256, 0, stream>>>(
            out_ent, q * 100, accX2, rowsum, out_mask, N);
    }

    // E. fused final GEMM + l2norm
    final_mfma_k<<<nblk, 256, 0, stream>>>(ent, nscale, btf, out_ent, N);
}

// Round 8
// 617.074 us; speedup vs baseline: 2.7610x; 1.4372x over previous
//
#include <hip/hip_runtime.h>
#include <hip/hip_bf16.h>
#include <math.h>

// SpKBGAT: N=50000, D=200, R=500, NHID=100, H=2, OD=200, E=150000, ENH=30000.
// R8: scatter->gather. dst-CSR built once per launch; aggregation = wave-per-dst
// gather, zero atomics, fused with attention-weight recompute + elu/combine.
#define DD   200
#define NHID 100
#define OD   200
#define KP   224   // padded K (7 chunks of 32)

typedef __attribute__((ext_vector_type(8))) short short8;
typedef __attribute__((ext_vector_type(4))) float f32x4;

static inline int cdiv(int a, int b) { return (a + b - 1) / b; }

__device__ inline float toF(float x) { return x; }
__device__ inline float toF(__hip_bfloat16 x) { return __bfloat162float(x); }
__device__ inline void storeC(float v, float* p) { *p = v; }
__device__ inline void storeC(float v, __hip_bfloat16* p) { *p = __float2bfloat16(v); }
__device__ inline short bf16s(float f) {
    __hip_bfloat16 h = __float2bfloat16(f);
    short s; __builtin_memcpy(&s, &h, 2); return s;
}

// -------- per-row inverse L2 norm (f32), wave per row --------
__global__ __launch_bounds__(256)
void rownorm_inv_k(const float* __restrict__ in, float* __restrict__ sc, int M, int Dd)
{
    int wave = (blockIdx.x * blockDim.x + threadIdx.x) >> 6;
    int lane = threadIdx.x & 63;
    if (wave >= M) return;
    float ss = 0.f;
    for (int k = lane; k < Dd; k += 64) {
        float x = in[(size_t)wave * Dd + k];
        ss += x * x;
    }
    for (int o = 32; o > 0; o >>= 1) ss += __shfl_down(ss, o);
    if (lane == 0) sc[wave] = 1.f / fmaxf(sqrtf(ss), 1e-12f);
}

// -------- B-panel prep: bf16 [col][KP], zero-padded --------
__global__ void prep_bt_l1(const float* __restrict__ ah, __hip_bfloat16* __restrict__ Bt)
{
    int c = blockIdx.x, k = threadIdx.x;
    if (k >= KP) return;
    int seg = c / 100, idx = c - seg * 100;
    int h = seg & 1, off = (seg >> 1) * 200;
    float v = (k < 200) ? ah[(size_t)(h * 100 + idx) * 600 + off + k] : 0.f;
    Bt[(size_t)c * KP + k] = __float2bfloat16(v);
}
__global__ void prep_bt_l2(const float* __restrict__ ao, __hip_bfloat16* __restrict__ Bt)
{
    int c = blockIdx.x, k = threadIdx.x;
    if (k >= KP) return;
    int row = (c < 200) ? c : c - 200;
    int off = (c < 200) ? 0 : 200;
    float v = (k < 200) ? ao[(size_t)row * 600 + off + k] : 0.f;
    Bt[(size_t)c * KP + k] = __float2bfloat16(v);
}
__global__ void prep_bt_fin(const float* __restrict__ W, __hip_bfloat16* __restrict__ Bt)
{
    int c = blockIdx.x, k = threadIdx.x;
    if (k >= KP) return;
    float v = (c < 200 && k < 200) ? W[(size_t)k * 200 + c] : 0.f;
    Bt[(size_t)c * KP + k] = __float2bfloat16(v);
}

// -------- layer-1 fused (both heads): 25 tiles = xa1_h0|xa1_h1|xa2_h0|xa2_h1
__global__ __launch_bounds__(256)
void l1_both_k(const float* __restrict__ ent, const float* __restrict__ nscale,
               const __hip_bfloat16* __restrict__ Bt,  // [400][KP]
               const float* __restrict__ a2h,          // [2][100]
               __hip_bfloat16* __restrict__ x1,        // [N][KP] (cols 0-199)
               __hip_bfloat16* __restrict__ pB,        // [2][N][100]
               float* __restrict__ s1, float* __restrict__ s2,  // [2][N]
               int M, size_t PN)
{
    int tid = threadIdx.x, wave = tid >> 6, lane = tid & 63;
    int quad = lane >> 4, l16 = lane & 15;
    int m0 = blockIdx.x * 64;
    int arow = m0 + wave * 16 + l16;
    bool rok = arow < M;
    float nsc = rok ? nscale[arow] : 0.f;
    const float* arp = ent + (size_t)arow * DD;

    f32x4 acc[25];
#pragma unroll
    for (int t = 0; t < 25; t++) acc[t] = (f32x4){0.f, 0.f, 0.f, 0.f};

    for (int ch = 0; ch < 7; ch++) {
        int kb = ch * 32 + quad * 8;
        float av[8];
        if (rok && kb + 8 <= DD) {
            const float4* p = (const float4*)(arp + kb);
            float4 u0 = p[0], u1 = p[1];
            av[0] = u0.x; av[1] = u0.y; av[2] = u0.z; av[3] = u0.w;
            av[4] = u1.x; av[5] = u1.y; av[6] = u1.z; av[7] = u1.w;
        } else {
#pragma unroll
            for (int j = 0; j < 8; j++) av[j] = (rok && kb + j < DD) ? arp[kb + j] : 0.f;
        }
        short8 a;
#pragma unroll
        for (int j = 0; j < 8; j++) a[j] = bf16s(av[j] * nsc);
        const __hip_bfloat16* bp = Bt + (size_t)l16 * KP + kb;
#pragma unroll
        for (int t = 0; t < 25; t++) {
            short8 b = *(const short8*)(bp + (size_t)t * 16 * KP);
            acc[t] = __builtin_amdgcn_mfma_f32_16x16x32_bf16(a, b, acc[t], 0, 0, 0);
        }
    }

    int orow = m0 + wave * 16 + quad * 4;
    float d0[4] = {0,0,0,0}, d1[4] = {0,0,0,0}, d2[4] = {0,0,0,0}, d3[4] = {0,0,0,0};
#pragma unroll
    for (int t = 0; t < 25; t++) {
        int c = t * 16 + l16;
        int seg = c / 100, idx = c - seg * 100;
        float w = a2h[(seg & 1) * 100 + idx];
#pragma unroll
        for (int i = 0; i < 4; i++) {
            float v = acc[t][i];
            float vw = v * w;
            if (seg == 0) d0[i] += vw;
            else if (seg == 1) d1[i] += vw;
            else if (seg == 2) d2[i] += vw;
            else d3[i] += vw;
            int gm = orow + i;
            if (gm < M) {
                if (seg < 2) x1[(size_t)gm * KP + c] = __float2bfloat16(v);
                else pB[(size_t)(seg - 2) * PN + (size_t)gm * 100 + idx] = __float2bfloat16(v);
            }
        }
    }
#pragma unroll
    for (int msk = 1; msk < 16; msk <<= 1)
#pragma unroll
        for (int i = 0; i < 4; i++) {
            d0[i] += __shfl_xor(d0[i], msk);
            d1[i] += __shfl_xor(d1[i], msk);
            d2[i] += __shfl_xor(d2[i], msk);
            d3[i] += __shfl_xor(d3[i], msk);
        }
    if (l16 == 0)
#pragma unroll
        for (int i = 0; i < 4; i++) {
            int gm = orow + i;
            if (gm < M) {
                s1[gm] = d0[i]; s1[M + gm] = d1[i];
                s2[gm] = d2[i]; s2[M + gm] = d3[i];
            }
        }
}

// -------- layer-2 fused: 25 tiles = x1A1 (f32 -> out_ent) | x1A2 (bf16) ----
__global__ __launch_bounds__(256)
void l2_proj_k(const __hip_bfloat16* __restrict__ x1,  // [N][KP]
               const __hip_bfloat16* __restrict__ Bt,  // [400][KP]
               const float* __restrict__ a2o,          // [200]
               float* __restrict__ x1A1,               // [N][200] (out_ent)
               __hip_bfloat16* __restrict__ x1A2,      // [N][200]
               float* __restrict__ s1, float* __restrict__ s2, int M)
{
    int tid = threadIdx.x, wave = tid >> 6, lane = tid & 63;
    int quad = lane >> 4, l16 = lane & 15;
    int m0 = blockIdx.x * 64;
    int arow = m0 + wave * 16 + l16;
    bool rok = arow < M;
    const __hip_bfloat16* arp = x1 + (size_t)arow * KP;

    f32x4 acc[25];
#pragma unroll
    for (int t = 0; t < 25; t++) acc[t] = (f32x4){0.f, 0.f, 0.f, 0.f};

    for (int ch = 0; ch < 7; ch++) {
        int kb = ch * 32 + quad * 8;
        short8 a = (short8){0,0,0,0,0,0,0,0};
        if (rok) a = *(const short8*)(arp + kb);
        const __hip_bfloat16* bp = Bt + (size_t)l16 * KP + kb;
#pragma unroll
        for (int t = 0; t < 25; t++) {
            short8 b = *(const short8*)(bp + (size_t)t * 16 * KP);
            acc[t] = __builtin_amdgcn_mfma_f32_16x16x32_bf16(a, b, acc[t], 0, 0, 0);
        }
    }

    int orow = m0 + wave * 16 + quad * 4;
    float dA[4] = {0,0,0,0}, dB[4] = {0,0,0,0};
#pragma unroll
    for (int t = 0; t < 25; t++) {
        int c = t * 16 + l16;
        bool first = c < 200;
        int cc = first ? c : c - 200;
        float w = a2o[cc];
#pragma unroll
        for (int i = 0; i < 4; i++) {
            float v = acc[t][i];
            int gm = orow + i;
            if (first) {
                dA[i] += v * w;
                if (gm < M) x1A1[(size_t)gm * OD + c] = v;
            } else {
                dB[i] += v * w;
                if (gm < M) x1A2[(size_t)gm * OD + cc] = __float2bfloat16(v);
            }
        }
    }
#pragma unroll
    for (int msk = 1; msk < 16; msk <<= 1)
#pragma unroll
        for (int i = 0; i < 4; i++) {
            dA[i] += __shfl_xor(dA[i], msk);
            dB[i] += __shfl_xor(dB[i], msk);
        }
    if (l16 == 0)
#pragma unroll
        for (int i = 0; i < 4; i++) {
            int gm = orow + i;
            if (gm < M) { s1[gm] = dA[i]; s2[gm] = dB[i]; }
        }
}

// -------- final: out_ent = l2norm(out_ent + (ent*nscale) @ W_ent) ---------
__global__ __launch_bounds__(256)
void final_mfma_k(const float* __restrict__ ent, const float* __restrict__ nscale,
                  const __hip_bfloat16* __restrict__ Bt,  // [208][KP]
                  float* __restrict__ outent, int M)
{
    int tid = threadIdx.x, wave = tid >> 6, lane = tid & 63;
    int quad = lane >> 4, l16 = lane & 15;
    int m0 = blockIdx.x * 64;
    int arow = m0 + wave * 16 + l16;
    bool rok = arow < M;
    float nsc = rok ? nscale[arow] : 0.f;
    const float* arp = ent + (size_t)arow * DD;

    f32x4 acc[13];
#pragma unroll
    for (int t = 0; t < 13; t++) acc[t] = (f32x4){0.f, 0.f, 0.f, 0.f};

    for (int ch = 0; ch < 7; ch++) {
        int kb = ch * 32 + quad * 8;
        float av[8];
        if (rok && kb + 8 <= DD) {
            const float4* p = (const float4*)(arp + kb);
            float4 u0 = p[0], u1 = p[1];
            av[0] = u0.x; av[1] = u0.y; av[2] = u0.z; av[3] = u0.w;
            av[4] = u1.x; av[5] = u1.y; av[6] = u1.z; av[7] = u1.w;
        } else {
#pragma unroll
            for (int j = 0; j < 8; j++) av[j] = (rok && kb + j < DD) ? arp[kb + j] : 0.f;
        }
        short8 a;
#pragma unroll
        for (int j = 0; j < 8; j++) a[j] = bf16s(av[j] * nsc);
        const __hip_bfloat16* bp = Bt + (size_t)l16 * KP + kb;
#pragma unroll
        for (int t = 0; t < 13; t++) {
            short8 b = *(const short8*)(bp + (size_t)t * 16 * KP);
            acc[t] = __builtin_amdgcn_mfma_f32_16x16x32_bf16(a, b, acc[t], 0, 0, 0);
        }
    }

    int orow = m0 + wave * 16 + quad * 4;
    float ss[4] = {0.f, 0.f, 0.f, 0.f};
#pragma unroll
    for (int t = 0; t < 13; t++) {
        int gn = t * 16 + l16;
#pragma unroll
        for (int i = 0; i < 4; i++) {
            int gm = orow + i;
            float v = 0.f;
            if (gn < OD && gm < M) v = acc[t][i] + outent[(size_t)gm * OD + gn];
            acc[t][i] = v;
            ss[i] += v * v;
        }
    }
#pragma unroll
    for (int msk = 1; msk < 16; msk <<= 1)
#pragma unroll
        for (int i = 0; i < 4; i++) ss[i] += __shfl_xor(ss[i], msk);
    float scl[4];
#pragma unroll
    for (int i = 0; i < 4; i++) scl[i] = 1.f / fmaxf(sqrtf(ss[i]), 1e-12f);
#pragma unroll
    for (int t = 0; t < 13; t++) {
        int gn = t * 16 + l16;
        if (gn >= OD) continue;
#pragma unroll
        for (int i = 0; i < 4; i++) {
            int gm = orow + i;
            if (gm < M) outent[(size_t)gm * OD + gn] = acc[t][i] * scl[i];
        }
    }
}

// -------- generic MFMA GEMM (small R-sized matmuls) --------
#define KPAD 48
template<bool BTr, typename AT, typename CT>
__global__ __launch_bounds__(256)
void gemm_mfma_k(const AT* __restrict__ A, int lda, const float* __restrict__ ascale,
                 const float* __restrict__ B, int ldb, int colOff,
                 CT* __restrict__ C, int ldc, int M, int Nc, int K)
{
    __shared__ __align__(16) __hip_bfloat16 As[64][KPAD];
    __shared__ __align__(16) __hip_bfloat16 Bs[64][KPAD];
    int tid  = threadIdx.x;
    int wave = tid >> 6, lane = tid & 63;
    int quad = lane >> 4, l16 = lane & 15;
    int n0 = blockIdx.x * 64, m0 = blockIdx.y * 64;
    f32x4 acc[4];
#pragma unroll
    for (int t = 0; t < 4; t++) acc[t] = (f32x4){0.f, 0.f, 0.f, 0.f};

    for (int k0 = 0; k0 < K; k0 += 32) {
        {
            int m = tid >> 2, kc = (tid & 3) * 8;
            int gm = m0 + m;
            float scale = (ascale && gm < M) ? ascale[gm] : 1.f;
#pragma unroll
            for (int j = 0; j < 8; j++) {
                int gk = k0 + kc + j;
                float v = 0.f;
                if (gm < M && gk < K) v = toF(A[(size_t)gm * lda + gk]) * scale;
                As[m][kc + j] = __float2bfloat16(v);
            }
        }
        if (BTr) {
            int n = tid >> 2, kc = (tid & 3) * 8;
            int gn = n0 + n;
#pragma unroll
            for (int j = 0; j < 8; j++) {
                int gk = k0 + kc + j;
                float v = 0.f;
                if (gn < Nc && gk < K) v = B[(size_t)gn * ldb + colOff + gk];
                Bs[n][kc + j] = __float2bfloat16(v);
            }
        } else {
            int n = tid & 63, kq = tid >> 6;
            int gn = n0 + n;
#pragma unroll
            for (int j = 0; j < 8; j++) {
                int gk = k0 + kq * 8 + j;
                float v = 0.f;
                if (gn < Nc && gk < K) v = B[(size_t)gk * ldb + gn];
                Bs[n][kq * 8 + j] = __float2bfloat16(v);
            }
        }
        __syncthreads();
        short8 a = *(const short8*)&As[wave * 16 + l16][quad * 8];
#pragma unroll
        for (int t = 0; t < 4; t++) {
            short8 b = *(const short8*)&Bs[t * 16 + l16][quad * 8];
            acc[t] = __builtin_amdgcn_mfma_f32_16x16x32_bf16(a, b, acc[t], 0, 0, 0);
        }
        __syncthreads();
    }
#pragma unroll
    for (int t = 0; t < 4; t++) {
        int gn = n0 + t * 16 + l16;
        if (gn >= Nc) continue;
#pragma unroll
        for (int i = 0; i < 4; i++) {
            int gm = m0 + wave * 16 + quad * 4 + i;
            if (gm < M) storeC(acc[t][i], &C[(size_t)gm * ldc + gn]);
        }
    }
}

// -------- row-dot (srel) --------
template<typename T>
__global__ __launch_bounds__(256)
void rowdot_k(const T* __restrict__ mat, int ld, int coff,
              const float* __restrict__ vec,
              float* __restrict__ outp, int M, int Dd)
{
    int wave = (blockIdx.x * blockDim.x + threadIdx.x) >> 6;
    int lane = threadIdx.x & 63;
    if (wave >= M) return;
    float s = 0.f;
    for (int k = lane; k < Dd; k += 64)
        s += toF(mat[(size_t)wave * ld + coff + k]) * vec[k];
    for (int o = 32; o > 0; o >>= 1) s += __shfl_down(s, o);
    if (lane == 0) outp[wave] = s;
}

// -------- CSR build --------
__device__ inline void decode_edge(const int* __restrict__ el, int E,
                                   const int* __restrict__ etype,
                                   const int* __restrict__ tin, int e,
                                   int& dst, int& src, int& r1, int& r2)
{
    if (e < E) { dst = el[e]; src = el[E + e]; r1 = etype[e]; r2 = -1; }
    else {
        int j = e - E;
        dst = tin[j * 4 + 3]; src = tin[j * 4 + 0];
        r1 = tin[j * 4 + 1];  r2 = tin[j * 4 + 2];
    }
}

__global__ void hist_k(const int* __restrict__ el, int E, const int* __restrict__ etype,
                       const int* __restrict__ tin, int Etot, int* __restrict__ cnt)
{
    int e = blockIdx.x * blockDim.x + threadIdx.x;
    if (e >= Etot) return;
    int dst, src, r1, r2; decode_edge(el, E, etype, tin, e, dst, src, r1, r2);
    atomicAdd(&cnt[dst], 1);
}

__global__ __launch_bounds__(1024)
void scan1_k(const int* __restrict__ cnt, int* __restrict__ start,
             int* __restrict__ aux, int n)
{
    __shared__ int tmp[1024];
    int i = blockIdx.x * 1024 + threadIdx.x;
    int v = (i < n) ? cnt[i] : 0;
    tmp[threadIdx.x] = v;
    __syncthreads();
    for (int o = 1; o < 1024; o <<= 1) {
        int t = (threadIdx.x >= (unsigned)o) ? tmp[threadIdx.x - o] : 0;
        __syncthreads();
        tmp[threadIdx.x] += t;
        __syncthreads();
    }
    if (i < n) start[i] = tmp[threadIdx.x] - v;
    if (threadIdx.x == 1023) aux[blockIdx.x] = tmp[1023];
}

__global__ void scan2_k(int* __restrict__ aux, int nb)
{
    if (threadIdx.x == 0 && blockIdx.x == 0) {
        int s = 0;
        for (int i = 0; i < nb; i++) { int v = aux[i]; aux[i] = s; s += v; }
    }
}

__global__ __launch_bounds__(1024)
void scan3_k(int* __restrict__ start, const int* __restrict__ aux, int n, int Etot)
{
    int i = blockIdx.x * 1024 + threadIdx.x;
    if (i < n) start[i] += aux[blockIdx.x];
    if (i == 0) start[n] = Etot;
}

__global__ void fill_k(const int* __restrict__ el, int E, const int* __restrict__ etype,
                       const int* __restrict__ tin, int Etot,
                       const int* __restrict__ start, int* __restrict__ fill,
                       int4* __restrict__ csr)
{
    int e = blockIdx.x * blockDim.x + threadIdx.x;
    if (e >= Etot) return;
    int dst, src, r1, r2; decode_edge(el, E, etype, tin, e, dst, src, r1, r2);
    int p = start[dst] + atomicAdd(&fill[dst], 1);
    csr[p] = make_int4(src, r1, r2, 0);
}

// -------- layer-1 gather (both heads), wave per dst; fused elu finalize ----
__global__ __launch_bounds__(256)
void gather_l1_k(const int* __restrict__ start, const int4* __restrict__ csr,
                 const float* __restrict__ s1, const float* __restrict__ s2, // [2][N]
                 const float* __restrict__ srel2, int R_,                    // [2][R]
                 const __hip_bfloat16* __restrict__ pB, size_t PN,           // [2][N][100]
                 const float* __restrict__ rpf2,                             // [2][R][100]
                 __hip_bfloat16* __restrict__ x1, int N)                     // [N][KP]
{
    int n = (blockIdx.x * blockDim.x + threadIdx.x) >> 6;
    int lane = threadIdx.x & 63;
    if (n >= N) return;
    int b0 = start[n], b1 = start[n + 1];
    float s1h0 = s1[n], s1h1 = s1[N + n];
    float rs0 = 0.f, rs1 = 0.f;
    float a00 = 0.f, a01 = 0.f, a10 = 0.f, a11 = 0.f;
    int k0 = lane, k1 = lane + 64;
    bool k1ok = k1 < 100;
    const float* rph1 = rpf2 + (size_t)R_ * 100;
    for (int idx = b0; idx < b1; idx++) {
        int4 eg = csr[idx];
        int src = eg.x, r1 = eg.y, r2 = eg.z;
        float sr0 = srel2[r1], sr1 = srel2[R_ + r1];
        const float* q0 = rpf2 + (size_t)r1 * 100;
        const float* q1 = rph1 + (size_t)r1 * 100;
        float v00 = q0[k0], v10 = q1[k0];
        float v01 = k1ok ? q0[k1] : 0.f, v11 = k1ok ? q1[k1] : 0.f;
        if (r2 >= 0) {
            sr0 += srel2[r2]; sr1 += srel2[R_ + r2];
            const float* t0 = rpf2 + (size_t)r2 * 100;
            const float* t1 = rph1 + (size_t)r2 * 100;
            v00 += t0[k0]; v10 += t1[k0];
            if (k1ok) { v01 += t0[k1]; v11 += t1[k1]; }
        }
        const __hip_bfloat16* p0 = pB + (size_t)src * 100;
        const __hip_bfloat16* p1 = pB + PN + (size_t)src * 100;
        v00 += toF(p0[k0]); v10 += toF(p1[k0]);
        if (k1ok) { v01 += toF(p0[k1]); v11 += toF(p1[k1]); }
        float z0 = s1h0 + s2[src] + sr0;
        float z1 = s1h1 + s2[N + src] + sr1;
        float w0 = expf(-(z0 > 0.f ? z0 : 0.2f * z0));
        float w1 = expf(-(z1 > 0.f ? z1 : 0.2f * z1));
        rs0 += w0; rs1 += w1;
        a00 += w0 * v00; a01 += w0 * v01;
        a10 += w1 * v10; a11 += w1 * v11;
    }
    float i0 = rs0 > 0.f ? 1.f / rs0 : 0.f;
    float i1 = rs1 > 0.f ? 1.f / rs1 : 0.f;
    __hip_bfloat16* xr = x1 + (size_t)n * KP;
    float hp;
    hp = rs0 > 0.f ? toF(xr[k0]) + a00 * i0 : 0.f;
    xr[k0] = __float2bfloat16(hp > 0.f ? hp : expf(hp) - 1.f);
    hp = rs1 > 0.f ? toF(xr[100 + k0]) + a10 * i1 : 0.f;
    xr[100 + k0] = __float2bfloat16(hp > 0.f ? hp : expf(hp) - 1.f);
    if (k1ok) {
        hp = rs0 > 0.f ? toF(xr[k1]) + a01 * i0 : 0.f;
        xr[k1] = __float2bfloat16(hp > 0.f ? hp : expf(hp) - 1.f);
        hp = rs1 > 0.f ? toF(xr[100 + k1]) + a11 * i1 : 0.f;
        xr[100 + k1] = __float2bfloat16(hp > 0.f ? hp : expf(hp) - 1.f);
    }
}

// -------- layer-2 gather, wave per dst; fused mask*elu combine ------------
__global__ __launch_bounds__(256)
void gather_l2_k(const int* __restrict__ start, const int4* __restrict__ csr,
                 const float* __restrict__ s1, const float* __restrict__ s2,
                 const float* __restrict__ srel,
                 const __hip_bfloat16* __restrict__ x1A2,  // [N][200]
                 const float* __restrict__ rpf,            // [R][200]
                 const float* __restrict__ maskf,
                 float* __restrict__ outent, int N)        // [N][200], holds x1A1
{
    int n = (blockIdx.x * blockDim.x + threadIdx.x) >> 6;
    int lane = threadIdx.x & 63;
    if (n >= N) return;
    int b0 = start[n], b1 = start[n + 1];
    float s1n = s1[n];
    float rs = 0.f;
    float a[4] = {0.f, 0.f, 0.f, 0.f};
    for (int idx = b0; idx < b1; idx++) {
        int4 eg = csr[idx];
        int src = eg.x, r1 = eg.y, r2 = eg.z;
        float sr = srel[r1] + (r2 >= 0 ? srel[r2] : 0.f);
        float z = s1n + s2[src] + sr;
        float w = expf(-(z > 0.f ? z : 0.2f * z));
        rs += w;
        const __hip_bfloat16* xs = x1A2 + (size_t)src * 200;
        const float* q1 = rpf + (size_t)r1 * 200;
        const float* q2 = (r2 >= 0) ? (rpf + (size_t)r2 * 200) : nullptr;
#pragma unroll
        for (int s = 0; s < 4; s++) {
            int k = lane + 64 * s;
            if (k < 200) {
                float v = toF(xs[k]) + q1[k] + (q2 ? q2[k] : 0.f);
                a[s] += w * v;
            }
        }
    }
    float inv = rs > 0.f ? 1.f / rs : 0.f;
    float mk = maskf[n];
    float* orow = outent + (size_t)n * 200;
#pragma unroll
    for (int s = 0; s < 4; s++) {
        int k = lane + 64 * s;
        if (k < 200) {
            float hp = rs > 0.f ? orow[k] + a[s] * inv : 0.f;
            float e = hp > 0.f ? hp : expf(hp) - 1.f;
            orow[k] = mk * e;
        }
    }
}

__global__ void scatter_mask_k(const int* __restrict__ batch, int NB,
                               float* __restrict__ masko)
{
    int i = blockIdx.x * blockDim.x + threadIdx.x;
    if (i >= NB) return;
    masko[batch[i]] = 1.0f;
}

extern "C" void kernel_launch(void* const* d_in, const int* in_sizes, int n_in,
                              void* d_out, int out_size, void* d_ws, size_t ws_size,
                              hipStream_t stream)
{
    const float* ent      = (const float*)d_in[0];
    const float* rel      = (const float*)d_in[1];
    const float* W_ent    = (const float*)d_in[2];
    const float* W_gat    = (const float*)d_in[3];
    const float* a_heads  = (const float*)d_in[4];
    const float* a2_heads = (const float*)d_in[5];
    const float* a_out    = (const float*)d_in[6];
    const float* a2_out   = (const float*)d_in[7];
    const int* batch = (const int*)d_in[8];
    const int* el    = (const int*)d_in[9];
    const int* etype = (const int*)d_in[10];
    const int* tin   = (const int*)d_in[11];

    const int N   = in_sizes[0] / DD;   // 50000
    const int R   = in_sizes[1] / DD;   // 500
    const int NB  = in_sizes[8];        // 20000
    const int E   = in_sizes[9] / 2;    // 150000
    const int ENH = in_sizes[11] / 4;   // 30000
    const int Etot = E + ENH;
    const size_t PN = (size_t)N * 100;

    // ---- workspace (~48 MB) ----
    char* ws = (char*)d_ws;
    size_t off = 0;
    auto take = [&](size_t bytes) { size_t o = off; off += (bytes + 255) & ~(size_t)255; return o; };
    size_t o_R1   = take((size_t)N * KP * 2);     // x1 bf16 [N][KP]
    size_t o_R2   = take((size_t)N * OD * 2);     // pB [2][N][100]; later x1A2 [N][200]
    size_t o_rpf  = take((size_t)2 * R * 100 * 4);// rpf2 [2][R][100] / layer2 rpf [R][200]
    size_t o_bt1  = take((size_t)400 * KP * 2);
    size_t o_bt2  = take((size_t)400 * KP * 2);
    size_t o_btf  = take((size_t)208 * KP * 2);
    size_t o_nsc  = take((size_t)N * 4);
    size_t o_s1   = take((size_t)2 * N * 4);
    size_t o_s2   = take((size_t)2 * N * 4);
    size_t o_srel = take((size_t)2 * R * 4);
    size_t o_csr  = take((size_t)Etot * 16);
    size_t o_cnt  = take((size_t)N * 4);
    size_t o_str  = take((size_t)(N + 1) * 4);
    size_t o_aux  = take((size_t)64 * 4);

    __hip_bfloat16* x1   = (__hip_bfloat16*)(ws + o_R1);
    __hip_bfloat16* pB   = (__hip_bfloat16*)(ws + o_R2); // [2][N][100]
    __hip_bfloat16* x1A2 = (__hip_bfloat16*)(ws + o_R2); // [N][200] after pB dead
    float* rpf2   = (float*)(ws + o_rpf);
    __hip_bfloat16* bt1 = (__hip_bfloat16*)(ws + o_bt1);
    __hip_bfloat16* bt2 = (__hip_bfloat16*)(ws + o_bt2);
    __hip_bfloat16* btf = (__hip_bfloat16*)(ws + o_btf);
    float* nscale = (float*)(ws + o_nsc);
    float* s1     = (float*)(ws + o_s1);
    float* s2     = (float*)(ws + o_s2);
    float* srel2  = (float*)(ws + o_srel);
    int4*  csr    = (int4*)(ws + o_csr);
    int*   cnt    = (int*)(ws + o_cnt);
    int*   startA = (int*)(ws + o_str);
    int*   aux    = (int*)(ws + o_aux);

    float* out       = (float*)d_out;
    float* out_ent   = out;                                     // [N,200]
    float* out_rel_o = out + (size_t)N * OD;                    // [500,200]
    float* out_mask  = out + (size_t)N * OD + (size_t)R * OD;   // [N]

    const int nblk = cdiv(N, 64);
    const int nbScan = cdiv(N, 1024);

    // A. prep: norms, B panels, x1 pad; out_rel GEMM
    rownorm_inv_k<<<cdiv(N, 4), 256, 0, stream>>>(ent, nscale, N, DD);
    prep_bt_l1<<<400, 256, 0, stream>>>(a_heads, bt1);
    prep_bt_l2<<<400, 256, 0, stream>>>(a_out, bt2);
    prep_bt_fin<<<208, 256, 0, stream>>>(W_ent, btf);
    hipMemsetAsync(x1, 0, (size_t)N * KP * 2, stream);
    gemm_mfma_k<false, float, float><<<dim3(cdiv(OD, 64), cdiv(R, 64)), 256, 0, stream>>>(
        rel, DD, nullptr, W_gat, OD, 0, out_rel_o, OD, R, OD, DD);

    // A2. CSR build (dst-grouped edge lists)
    hipMemsetAsync(cnt, 0, (size_t)N * 4, stream);
    hist_k<<<cdiv(Etot, 256), 256, 0, stream>>>(el, E, etype, tin, Etot, cnt);
    scan1_k<<<nbScan, 1024, 0, stream>>>(cnt, startA, aux, N);
    scan2_k<<<1, 64, 0, stream>>>(aux, nbScan);
    scan3_k<<<nbScan, 1024, 0, stream>>>(startA, aux, N, Etot);
    hipMemsetAsync(cnt, 0, (size_t)N * 4, stream);
    fill_k<<<cdiv(Etot, 256), 256, 0, stream>>>(el, E, etype, tin, Etot, startA, cnt, csr);

    // B. layer-1 projections (both heads) + rel projections + gather
    l1_both_k<<<nblk, 256, 0, stream>>>(ent, nscale, bt1, a2_heads, x1, pB, s1, s2, N, PN);
    for (int h = 0; h < 2; h++) {
        const float* ah  = a_heads + (size_t)h * NHID * 600;
        const float* a2h = a2_heads + (size_t)h * NHID;
        gemm_mfma_k<true, float, float><<<dim3(cdiv(NHID, 64), cdiv(R, 64)), 256, 0, stream>>>(
            rel, DD, nullptr, ah, 600, 400, rpf2 + (size_t)h * R * NHID, NHID, R, NHID, DD);
        rowdot_k<float><<<cdiv(R, 4), 256, 0, stream>>>(
            rpf2 + (size_t)h * R * NHID, NHID, 0, a2h, srel2 + (size_t)h * R, R, NHID);
    }
    gather_l1_k<<<cdiv(N, 4), 256, 0, stream>>>(
        startA, csr, s1, s2, srel2, R, pB, PN, rpf2, x1, N);
    // pB dead; R2 becomes x1A2.

    // C. layer-2 projection + rel side
    l2_proj_k<<<nblk, 256, 0, stream>>>(x1, bt2, a2_out, out_ent, x1A2, s1, s2, N);
    gemm_mfma_k<true, float, float><<<dim3(cdiv(OD, 64), cdiv(R, 64)), 256, 0, stream>>>(
        out_rel_o, OD, nullptr, a_out, 600, 400, rpf2, OD, R, OD, OD);
    rowdot_k<float><<<cdiv(R, 4), 256, 0, stream>>>(rpf2, OD, 0, a2_out, srel2, R, OD);

    // D. mask; layer-2 gather (fused combine, single 200-wide pass)
    hipMemsetAsync(out_mask, 0, (size_t)N * 4, stream);
    scatter_mask_k<<<cdiv(NB, 256), 256, 0, stream>>>(batch, NB, out_mask);
    gather_l2_k<<<cdiv(N, 4), 256, 0, stream>>>(
        startA, csr, s1, s2, srel2, x1A2, rpf2, out_mask, out_ent, N);

    // E. fused final GEMM + l2norm
    final_mfma_k<<<nblk, 256, 0, stream>>>(ent, nscale, btf, out_ent, N);
}